// Round 1
// 4687.199 us; speedup vs baseline: 1.0660x; 1.0660x over previous
//
#include <hip/hip_runtime.h>
#include <cstdint>

#define TT 1024
#define BB 128
#define DD 512
#define HH 256
#define TBR (TT*BB)   // 131072 rows

typedef __attribute__((ext_vector_type(8))) short  s8v;     // 8 bf16 (4 VGPR)
typedef __attribute__((ext_vector_type(4))) float  f4v;     // MFMA acc
typedef __attribute__((ext_vector_type(4))) unsigned u4v;

__device__ __forceinline__ float sigf(float x) {
    // fast sigmoid: v_exp + v_rcp. inf-safe: x->-inf: exp=inf -> rcp=0; x->+inf: ->1.
    return __builtin_amdgcn_rcpf(1.0f + __expf(-x));
}
__device__ __forceinline__ float tanh_fast(float x) {
    // tanh(x) = sign(x) * (1 - 2/(e^{2|x|}+1)); e=inf -> 1. ~1e-7 abs error.
    float e = __expf(fabsf(x) * 2.0f);
    float t = 1.0f - 2.0f * __builtin_amdgcn_rcpf(e + 1.0f);
    return copysignf(t, x);
}

__device__ __forceinline__ unsigned rnbf(float f) {         // fp32 -> bf16 bits (RN)
    unsigned u = __builtin_bit_cast(unsigned, f);
    return (u + 0x7FFFu + ((u >> 16) & 1u)) >> 16;
}

// ---------------------------------------------------------------------------
// Old packing (fallback path): r = gate*256 + h.
// ---------------------------------------------------------------------------
__global__ __launch_bounds__(256) void pack_kernel(
    const float* __restrict__ fw, const float* __restrict__ iw,
    const float* __restrict__ uw, const float* __restrict__ ow,
    const float* __restrict__ fb, const float* __restrict__ ib,
    const float* __restrict__ ub, const float* __restrict__ obb,
    float* __restrict__ wx_p, float* __restrict__ wh_p, float* __restrict__ b_p)
{
    const int r = blockIdx.x;
    const int gate = r >> 8, h = r & 255;
    const float* wsrc = gate == 0 ? fw : gate == 1 ? iw : gate == 2 ? uw : ow;
    const float* bsrc = gate == 0 ? fb : gate == 1 ? ib : gate == 2 ? ub : obb;
    const int k = threadIdx.x;
    wx_p[(size_t)r * 256 + k] = wsrc[(size_t)h * 512 + k];
    wh_p[(size_t)r * 256 + k] = wsrc[(size_t)h * 512 + 256 + k];
    if (k == 0) b_p[r] = bsrc[h];
}

// ---------------------------------------------------------------------------
// MFMA packing: r = hg*128 + g*32 + hrem, h = hg*32 + hrem  (hg=0..7).
// ---------------------------------------------------------------------------
__global__ __launch_bounds__(256) void pack_mfma(
    const float* __restrict__ fw, const float* __restrict__ iw,
    const float* __restrict__ uw, const float* __restrict__ ow,
    const float* __restrict__ fb, const float* __restrict__ ib,
    const float* __restrict__ ub, const float* __restrict__ obb,
    float* __restrict__ wx_p, float* __restrict__ wh_p, float* __restrict__ b_p)
{
    const int r = blockIdx.x;                 // 0..1023
    const int gate = (r >> 5) & 3;
    const int h = (r >> 7) * 32 + (r & 31);
    const float* wsrc = gate == 0 ? fw : gate == 1 ? iw : gate == 2 ? uw : ow;
    const float* bsrc = gate == 0 ? fb : gate == 1 ? ib : gate == 2 ? ub : obb;
    const int k = threadIdx.x;
    wx_p[(size_t)r * 256 + k] = wsrc[(size_t)h * 512 + k];
    wh_p[(size_t)r * 256 + k] = wsrc[(size_t)h * 512 + 256 + k];
    if (k == 0) b_p[r] = bsrc[h];
}

// ---------------------------------------------------------------------------
// fp32 GEMM: C[m][n] = act(dot(A[m][:K], W[n][:K]) + bias[n]). 128x128 tile.
// ---------------------------------------------------------------------------
template<int K, int ACT, int PERM>
__global__ __launch_bounds__(256) void gemm_kernel(
    const float* A, const float* __restrict__ W,
    const float* __restrict__ bias, float* C, int N)
{
    __shared__ __align__(16) float As[16][192];
    __shared__ __align__(16) float Wt[16][192];
    const int tid = threadIdx.x;
    const int m0 = blockIdx.x * 128, n0 = blockIdx.y * 128;
    const int tm = tid >> 4, tn = tid & 15;
    const int am = tm * 12, wn = tn * 12;
    float acc[8][8] = {};
    for (int kc = 0; kc < K; kc += 16) {
        #pragma unroll
        for (int i = 0; i < 2; ++i) {
            int f4 = tid + 256 * i;
            int r = f4 >> 2, k4 = (f4 & 3) * 4;
            float4 av = *(const float4*)&A[(size_t)(m0 + r) * K + kc + k4];
            float4 wv = *(const float4*)&W[(size_t)(n0 + r) * K + kc + k4];
            int fo = (r >> 3) * 12 + (r & 7);
            As[k4 + 0][fo] = av.x; As[k4 + 1][fo] = av.y;
            As[k4 + 2][fo] = av.z; As[k4 + 3][fo] = av.w;
            Wt[k4 + 0][fo] = wv.x; Wt[k4 + 1][fo] = wv.y;
            Wt[k4 + 2][fo] = wv.z; Wt[k4 + 3][fo] = wv.w;
        }
        __syncthreads();
        #pragma unroll
        for (int kk = 0; kk < 16; ++kk) {
            float a[8], w[8];
            *(float4*)&a[0] = *(const float4*)&As[kk][am];
            *(float4*)&a[4] = *(const float4*)&As[kk][am + 4];
            *(float4*)&w[0] = *(const float4*)&Wt[kk][wn];
            *(float4*)&w[4] = *(const float4*)&Wt[kk][wn + 4];
            #pragma unroll
            for (int i = 0; i < 8; ++i)
                #pragma unroll
                for (int j = 0; j < 8; ++j)
                    acc[i][j] = fmaf(a[i], w[j], acc[i][j]);
        }
        __syncthreads();
    }
    #pragma unroll
    for (int i = 0; i < 8; ++i) {
        int m = m0 + tm * 8 + i;
        #pragma unroll
        for (int jh = 0; jh < 2; ++jh) {
            float4 v; float* vp = (float*)&v;
            #pragma unroll
            for (int l = 0; l < 4; ++l) {
                int n = n0 + tn * 8 + jh * 4 + l;
                float t = acc[i][jh * 4 + l] + bias[n];
                if (ACT == 1) t = tanhf(t);
                if (ACT == 2) t = fmaxf(t, 0.0f);
                vp[l] = t;
            }
            int nb = n0 + tn * 8 + jh * 4;
            int nc = PERM ? (((nb & 255) >> 3) * 32 + ((nb >> 8) << 3) + (nb & 7)) : nb;
            *(float4*)&C[(size_t)m * N + nc] = v;
        }
    }
}

// ---------------------------------------------------------------------------
// MFMA recurrence with data-embedded sentinel sync.
// 64 WGs = 8 bg(16 batches) x 8 hg(128 packed gate rows). Wh resident in
// VGPRs as split-bf16 B-fragments.
//
// Sync redesign (this round): hx is published as single 8B atoms
// {hb0|hb1<<16 | (lb0|lb1<<16)<<32} into a depth-4 ring; consumers poll the
// DATA itself against sentinel ~0ull (bf16 0xFFFF = -NaN, unproducible by
// rnbf(o*tanh(cx)) which yields finite values in [-1,1]). This collapses the
// old {vmcnt(0) drain -> flag store -> flag poll -> hx load} four-L3-hop
// chain into one one-way store->poll-hit propagation. A WG re-sentinels its
// own cells of slot (t-2)&3 only AFTER its step-t poll succeeds: seeing all
// 8 group members' t-1 outputs proves they all finished consuming slot t-2
// (poll precedes publish in program order), so no peer can still be polling
// that slot. The vmcnt(0) the compiler emits inside every poll iteration
// drains the re-sentinel store long before the slot is rewritten at t+2.
// Two __syncthreads per step suffice (ldsH overwrite at t+1 is fenced by the
// post-MFMA barrier of t; pre[] overwrite at t+1 is fenced by the pre-MFMA
// barrier of t+1).
// ---------------------------------------------------------------------------
__global__ __launch_bounds__(256, 1) void recur_mfma(
    float* __restrict__ h_buf,            // out: hs [T][B][256] fp32
    const float* __restrict__ xg,         // [TBR][1024] packed cols, fp32
    const float* __restrict__ wh_mf,      // [1024][256] packed
    unsigned long long* __restrict__ ring) // [4][128][128] 8B atoms, 0xFF-filled
{
    __shared__ __align__(16) unsigned ldsH[16 * 128];
    __shared__ __align__(16) unsigned ldsL[16 * 128];
    __shared__ float pre[16][132];
    const int tid = threadIdx.x;
    const int lane = tid & 63;
    const int wv = tid >> 6;
    const int bg = blockIdx.x & 7, hg = blockIdx.x >> 3;
    const int b0 = bg * 16;
    const int nlo = lane & 15, quad = lane >> 4;

    // ---- one-time: Wh -> registers as split-bf16 B-fragments
    s8v bh[2][8], bl[2][8];
    #pragma unroll
    for (int nt = 0; nt < 2; ++nt) {
        int r = hg * 128 + wv * 32 + nt * 16 + nlo;
        #pragma unroll
        for (int ks = 0; ks < 8; ++ks) {
            const float* src = wh_mf + (size_t)r * 256 + ks * 32 + quad * 8;
            u4v uh, ul;
            #pragma unroll
            for (int p = 0; p < 4; ++p) {
                float f0 = src[2 * p], f1 = src[2 * p + 1];
                unsigned h0 = rnbf(f0), h1 = rnbf(f1);
                float r0 = f0 - __builtin_bit_cast(float, h0 << 16);
                float r1 = f1 - __builtin_bit_cast(float, h1 << 16);
                uh[p] = h0 | (h1 << 16);
                ul[p] = rnbf(r0) | (rnbf(r1) << 16);
            }
            bh[nt][ks] = __builtin_bit_cast(s8v, uh);
            bl[nt][ks] = __builtin_bit_cast(s8v, ul);
        }
    }

    const int sm = tid >> 4;             // staging row 0..15
    const int sc0 = (tid & 15) * 2;      // first of 2 dword-quads per thread
    const int cb = tid >> 4, q = tid & 15;  // combine: batch row, h-pair
    const unsigned long long SENT = ~0ull;

    float cx0 = 0.0f, cx1 = 0.0f;

    for (int t = 0; t < TT; ++t) {
        // prefetch xg for this step (plain loads; latency hides under poll)
        float2 xq[4];
        {
            const float* xr = xg + ((size_t)t * BB + b0 + cb) * 1024 + hg * 128 + 2 * q;
            #pragma unroll
            for (int g = 0; g < 4; ++g)
                xq[g] = *(const float2*)&xr[g * 32];
        }

        const int p0 = sm * 128 + ((sc0 ^ (sm & 7)) << 2);
        const int p1 = sm * 128 + (((sc0 + 1) ^ (sm & 7)) << 2);

        if (t == 0) {
            // initial state h(-1) = 0
            u4v z = {0u, 0u, 0u, 0u};
            *(u4v*)&ldsH[p0] = z; *(u4v*)&ldsH[p1] = z;
            *(u4v*)&ldsL[p0] = z; *(u4v*)&ldsL[p1] = z;
        } else {
            // poll directly on the hx atoms of slot (t-1)&3 (this thread's
            // 8 atoms all come from one producer WG of the same bg group)
            unsigned long long* src =
                ring + ((size_t)((t - 1) & 3) * 128 + b0 + sm) * 128 + sc0 * 4;
            unsigned long long a[8];
            long bud = 1L << 22;
            for (;;) {
                #pragma unroll
                for (int i = 0; i < 8; ++i)
                    a[i] = __hip_atomic_load(&src[i], __ATOMIC_RELAXED,
                                             __HIP_MEMORY_SCOPE_AGENT);
                bool ok = true;
                #pragma unroll
                for (int i = 0; i < 8; ++i) ok = ok && (a[i] != SENT);
                if (__all(ok)) break;
                if (--bud < 0) break;
                __builtin_amdgcn_s_sleep(1);
            }
            // unpack: lo dwords -> hi plane, hi dwords -> lo plane
            u4v w0 = { (unsigned)a[0], (unsigned)a[1], (unsigned)a[2], (unsigned)a[3] };
            u4v w1 = { (unsigned)a[4], (unsigned)a[5], (unsigned)a[6], (unsigned)a[7] };
            u4v v0 = { (unsigned)(a[0] >> 32), (unsigned)(a[1] >> 32),
                       (unsigned)(a[2] >> 32), (unsigned)(a[3] >> 32) };
            u4v v1 = { (unsigned)(a[4] >> 32), (unsigned)(a[5] >> 32),
                       (unsigned)(a[6] >> 32), (unsigned)(a[7] >> 32) };
            *(u4v*)&ldsH[p0] = w0; *(u4v*)&ldsH[p1] = w1;
            *(u4v*)&ldsL[p0] = v0; *(u4v*)&ldsL[p1] = v1;

            // safe to re-sentinel own cell of slot (t-2): poll success proves
            // all group members consumed it. Drained by next step's poll.
            if (t >= 2) {
                __hip_atomic_store(
                    &ring[((size_t)((t - 2) & 3) * 128 + b0 + cb) * 128 + hg * 16 + q],
                    SENT, __ATOMIC_RELAXED, __HIP_MEMORY_SCOPE_AGENT);
            }
        }
        __syncthreads();

        // MFMA: acc[nt] = sum_k (Whi*xhi + Whi*xlo + Wlo*xhi)
        f4v acc0 = {0.f, 0.f, 0.f, 0.f}, acc1 = {0.f, 0.f, 0.f, 0.f};
        #pragma unroll
        for (int ks = 0; ks < 8; ++ks) {
            int off = nlo * 128 + ((((ks * 4 + quad) ^ (nlo & 7))) << 2);
            s8v ah = __builtin_bit_cast(s8v, *(const u4v*)&ldsH[off]);
            s8v al = __builtin_bit_cast(s8v, *(const u4v*)&ldsL[off]);
            acc0 = __builtin_amdgcn_mfma_f32_16x16x32_bf16(ah, bh[0][ks], acc0, 0, 0, 0);
            acc1 = __builtin_amdgcn_mfma_f32_16x16x32_bf16(ah, bh[1][ks], acc1, 0, 0, 0);
            acc0 = __builtin_amdgcn_mfma_f32_16x16x32_bf16(al, bh[0][ks], acc0, 0, 0, 0);
            acc1 = __builtin_amdgcn_mfma_f32_16x16x32_bf16(al, bh[1][ks], acc1, 0, 0, 0);
            acc0 = __builtin_amdgcn_mfma_f32_16x16x32_bf16(ah, bl[0][ks], acc0, 0, 0, 0);
            acc1 = __builtin_amdgcn_mfma_f32_16x16x32_bf16(ah, bl[1][ks], acc1, 0, 0, 0);
        }
        // C-frags -> pre[m][n]
        {
            int n0c = wv * 32 + nlo;
            #pragma unroll
            for (int reg = 0; reg < 4; ++reg) {
                pre[quad * 4 + reg][n0c]      = acc0[reg];
                pre[quad * 4 + reg][n0c + 16] = acc1[reg];
            }
        }
        __syncthreads();

        // local gate combine: thread owns cells (b0+cb, hg*32+2q / +1)
        float2 pf = *(const float2*)&pre[cb][0 * 32 + 2 * q];
        float2 pi = *(const float2*)&pre[cb][1 * 32 + 2 * q];
        float2 pg = *(const float2*)&pre[cb][2 * 32 + 2 * q];
        float2 po = *(const float2*)&pre[cb][3 * 32 + 2 * q];
        float f0 = sigf(pf.x + xq[0].x), f1 = sigf(pf.y + xq[0].y);
        float i0 = sigf(pi.x + xq[1].x), i1 = sigf(pi.y + xq[1].y);
        float g0 = tanh_fast(pg.x + xq[2].x), g1 = tanh_fast(pg.y + xq[2].y);
        float o0 = sigf(po.x + xq[3].x), o1 = sigf(po.y + xq[3].y);
        cx0 = f0 * cx0 + i0 * g0;
        cx1 = f1 * cx1 + i1 * g1;
        float hv0 = o0 * tanh_fast(cx0);
        float hv1 = o1 * tanh_fast(cx1);

        // publish: single 8B self-validating atom (hi|lo packed). No drain,
        // no flag, no extra barrier — the data IS the signal.
        unsigned hb0 = rnbf(hv0), hb1 = rnbf(hv1);
        float l0 = hv0 - __builtin_bit_cast(float, hb0 << 16);
        float l1 = hv1 - __builtin_bit_cast(float, hb1 << 16);
        unsigned long long atom =
            (unsigned long long)(hb0 | (hb1 << 16)) |
            ((unsigned long long)(rnbf(l0) | (rnbf(l1) << 16)) << 32);
        __hip_atomic_store(
            &ring[((size_t)(t & 3) * 128 + b0 + cb) * 128 + hg * 16 + q],
            atom, __ATOMIC_RELAXED, __HIP_MEMORY_SCOPE_AGENT);
        *(float2*)&h_buf[((size_t)t * BB + b0 + cb) * 256 + hg * 32 + 2 * q] =
            make_float2(hv0, hv1);
    }
}

// ---------------------------------------------------------------------------
// Fallback scalar recurrence (old packing), used if ws too small for xg.
// ---------------------------------------------------------------------------
__device__ __forceinline__ int swz(int row, int k4) {
    return row * 256 + (((k4 ^ (row & 7)) & 63) << 2);
}

__global__ __launch_bounds__(256, 1) void recur_kernel(
    float* h_buf, const float* __restrict__ xg,
    const float* __restrict__ wx_p, const float* __restrict__ wh_p,
    const float* __restrict__ b_p, float* hx_buf, int* flags, int use_xg)
{
    __shared__ __align__(16) float Ws[32 * 256];
    __shared__ __align__(16) float Ss[32 * 256];
    const int tid = threadIdx.x;
    const int lane = tid & 63;
    const int bg = blockIdx.x & 3, hg = blockIdx.x >> 2;
    const int b0 = bg * 32;
    const int b = tid >> 3, h = tid & 7;
    const int wrow = tid >> 3;
    const int wkb = (tid & 7) * 32;

    float bias0 = b_p[0 * 256 + hg * 8 + h];
    float bias1 = b_p[1 * 256 + hg * 8 + h];
    float bias2 = b_p[2 * 256 + hg * 8 + h];
    float bias3 = b_p[3 * 256 + hg * 8 + h];
    __syncthreads();

    float cx = 0.0f, pv = 0.0f;

    for (int t = 0; t < TT; ++t) {
        if (t > 0) {
            const int* fp = flags + (size_t)(t - 1) * 128 + bg * 32 + (lane & 31);
            long bud = 1L << 22;
            for (;;) {
                int v = __hip_atomic_load(fp, __ATOMIC_RELAXED, __HIP_MEMORY_SCOPE_AGENT);
                if (__all(v != 0)) break;
                if (--bud < 0) break;
                __builtin_amdgcn_s_sleep(1);
            }
        }
        float acc0, acc1, acc2, acc3;
        {
            if (t > 0)
                h_buf[((size_t)(t - 1) * BB + b0 + b) * 256 + hg * 8 + h] = pv;
            acc0 = bias0; acc1 = bias1; acc2 = bias2; acc3 = bias3;
            {
                const int R = (wrow >> 3) * 256 + hg * 8 + (wrow & 7);
                const float* src = wx_p + (size_t)R * 256 + wkb;
                #pragma unroll
                for (int j = 0; j < 8; ++j)
                    *(float4*)&Ws[swz(wrow, (wkb >> 2) + j)] = *(const float4*)&src[j * 4];
                const float* hs = h_buf + ((size_t)t * BB + b0) * HH;
                #pragma unroll
                for (int i = 0; i < 32; ++i)
                    Ss[i * 256 + ((((tid >> 2) ^ (i & 7)) & 63) << 2) + (tid & 3)] =
                        hs[i * 256 + tid];
            }
            __syncthreads();
            #pragma unroll 4
            for (int k4 = 0; k4 < 64; ++k4) {
                float4 s  = *(const float4*)&Ss[swz(b, k4)];
                float4 w0 = *(const float4*)&Ws[(0 * 8 + h) * 256 + (((k4 ^ h) & 63) << 2)];
                float4 w1 = *(const float4*)&Ws[(1 * 8 + h) * 256 + (((k4 ^ h) & 63) << 2)];
                float4 w2 = *(const float4*)&Ws[(2 * 8 + h) * 256 + (((k4 ^ h) & 63) << 2)];
                float4 w3 = *(const float4*)&Ws[(3 * 8 + h) * 256 + (((k4 ^ h) & 63) << 2)];
                acc0 += s.x*w0.x + s.y*w0.y + s.z*w0.z + s.w*w0.w;
                acc1 += s.x*w1.x + s.y*w1.y + s.z*w1.z + s.w*w1.w;
                acc2 += s.x*w2.x + s.y*w2.y + s.z*w2.z + s.w*w2.w;
                acc3 += s.x*w3.x + s.y*w3.y + s.z*w3.z + s.w*w3.w;
            }
            __syncthreads();
            {
                const int R = (wrow >> 3) * 256 + hg * 8 + (wrow & 7);
                const float* src = wh_p + (size_t)R * 256 + wkb;
                #pragma unroll
                for (int j = 0; j < 8; ++j)
                    *(float4*)&Ws[swz(wrow, (wkb >> 2) + j)] = *(const float4*)&src[j * 4];
            }
        }
        {
            const float* hxr = hx_buf + (size_t)(t & 1) * (BB * HH) + (size_t)b0 * HH;
            #pragma unroll
            for (int i = 0; i < 32; ++i) {
                float v = __hip_atomic_load(&hxr[i * 256 + tid],
                                            __ATOMIC_RELAXED, __HIP_MEMORY_SCOPE_AGENT);
                Ss[i * 256 + ((((tid >> 2) ^ (i & 7)) & 63) << 2) + (tid & 3)] = v;
            }
        }
        __syncthreads();
        #pragma unroll 4
        for (int k4 = 0; k4 < 64; ++k4) {
            float4 s  = *(const float4*)&Ss[swz(b, k4)];
            float4 w0 = *(const float4*)&Ws[(0 * 8 + h) * 256 + (((k4 ^ h) & 63) << 2)];
            float4 w1 = *(const float4*)&Ws[(1 * 8 + h) * 256 + (((k4 ^ h) & 63) << 2)];
            float4 w2 = *(const float4*)&Ws[(2 * 8 + h) * 256 + (((k4 ^ h) & 63) << 2)];
            float4 w3 = *(const float4*)&Ws[(3 * 8 + h) * 256 + (((k4 ^ h) & 63) << 2)];
            acc0 += s.x*w0.x + s.y*w0.y + s.z*w0.z + s.w*w0.w;
            acc1 += s.x*w1.x + s.y*w1.y + s.z*w1.z + s.w*w1.w;
            acc2 += s.x*w2.x + s.y*w2.y + s.z*w2.z + s.w*w2.w;
            acc3 += s.x*w3.x + s.y*w3.y + s.z*w3.z + s.w*w3.w;
        }
        __syncthreads();

        float fg = sigf(acc0), ig = sigf(acc1), gg = tanhf(acc2), og = sigf(acc3);
        cx = fg * cx + ig * gg;
        float hxv = og * tanhf(cx);
        pv = hxv;

        __hip_atomic_store(
            &hx_buf[(size_t)((t + 1) & 1) * (BB * HH) + (size_t)(b0 + b) * HH + hg * 8 + h],
            hxv, __ATOMIC_RELAXED, __HIP_MEMORY_SCOPE_AGENT);
        asm volatile("s_waitcnt vmcnt(0)" ::: "memory");
        __syncthreads();
        if (tid == 0)
            __hip_atomic_store(&flags[(size_t)t * 128 + bg * 32 + hg], 1,
                               __ATOMIC_RELAXED, __HIP_MEMORY_SCOPE_AGENT);
    }

    {
        const int* fp = flags + (size_t)1023 * 128 + bg * 32 + (lane & 31);
        long bud = 1L << 22;
        for (;;) {
            int v = __hip_atomic_load(fp, __ATOMIC_RELAXED, __HIP_MEMORY_SCOPE_AGENT);
            if (__all(v != 0)) break;
            if (--bud < 0) break;
            __builtin_amdgcn_s_sleep(1);
        }
        h_buf[((size_t)1023 * BB + b0 + b) * 256 + hg * 8 + h] = pv;
    }
}

// ---------------------------------------------------------------------------
__global__ __launch_bounds__(256) void final_kernel(
    const float* __restrict__ z, const float* __restrict__ w2,
    const float* __restrict__ b2, float* __restrict__ out)
{
    const int m = blockIdx.x * 128 + (threadIdx.x >> 1);
    const int c = threadIdx.x & 1;
    const float* zr = z + (size_t)m * 256;
    const float* wr = w2 + (size_t)c * 256;
    float s = b2[c];
    #pragma unroll 8
    for (int k = 0; k < 256; k += 4) {
        float4 zv = *(const float4*)&zr[k];
        float4 wv = *(const float4*)&wr[k];
        s += zv.x*wv.x + zv.y*wv.y + zv.z*wv.z + zv.w*wv.w;
    }
    out[(size_t)m * 2 + c] = s;
}

// ---------------------------------------------------------------------------
extern "C" void kernel_launch(void* const* d_in, const int* in_sizes, int n_in,
                              void* d_out, int out_size, void* d_ws, size_t ws_size,
                              hipStream_t stream) {
    const float* x    = (const float*)d_in[0];
    const float* fc_w = (const float*)d_in[1];
    const float* fc_b = (const float*)d_in[2];
    const float* fw   = (const float*)d_in[3];
    const float* fb   = (const float*)d_in[4];
    const float* iw   = (const float*)d_in[5];
    const float* ib   = (const float*)d_in[6];
    const float* uw   = (const float*)d_in[7];
    const float* ub   = (const float*)d_in[8];
    const float* ow   = (const float*)d_in[9];
    const float* ob   = (const float*)d_in[10];
    const float* w0   = (const float*)d_in[11];
    const float* b0   = (const float*)d_in[12];
    const float* w1   = (const float*)d_in[13];
    const float* b1   = (const float*)d_in[14];
    const float* w2   = (const float*)d_in[15];
    const float* b2   = (const float*)d_in[16];
    float* out = (float*)d_out;

    // Workspace layout byte-identical to previous rounds.
    float* ws = (float*)d_ws;
    size_t off = 0;
    float* h_buf  = ws + off; off += (size_t)TBR * HH;     // 33,554,432 f
    float* wx_p   = ws + off; off += 1024 * 256;           // also wx_mf
    float* wh_p   = ws + off; off += 1024 * 256;           // also wh_mf
    float* b_p    = ws + off; off += 1024;                 // also b_mf
    float* hx_buf = ws + off; off += 2 * BB * HH;          // fallback only
    float* sync_f = ws + off; off += 131072;               // ring / flags
    const size_t base_f = off;
    float* xg = ws + base_f;
    const size_t need_xg = (base_f + (size_t)TBR * 1024) * sizeof(float);
    const int use_xg = (ws_size >= need_xg) ? 1 : 0;
    float* z0 = use_xg ? xg : (ws + base_f);

    if (use_xg) {
        // sentinel-fill the depth-4 hx ring (4*128*128 atoms * 8B = 512 KB)
        hipMemsetAsync(sync_f, 0xFF, 131072 * sizeof(float), stream);
        pack_mfma<<<1024, 256, 0, stream>>>(fw, iw, uw, ow, fb, ib, ub, ob,
                                            wx_p, wh_p, b_p);
        gemm_kernel<512, 1, 0><<<dim3(TBR / 128, 2), 256, 0, stream>>>(
            x, fc_w, fc_b, h_buf, 256);
        gemm_kernel<256, 0, 0><<<dim3(TBR / 128, 8), 256, 0, stream>>>(
            h_buf, wx_p, b_p, xg, 1024);
        recur_mfma<<<64, 256, 0, stream>>>(h_buf, xg, wh_p,
                                           (unsigned long long*)sync_f);
    } else {
        hipMemsetAsync(hx_buf, 0, (2 * BB * HH + 131072) * sizeof(float), stream);
        pack_kernel<<<1024, 256, 0, stream>>>(fw, iw, uw, ow, fb, ib, ub, ob,
                                              wx_p, wh_p, b_p);
        gemm_kernel<512, 1, 0><<<dim3(TBR / 128, 2), 256, 0, stream>>>(
            x, fc_w, fc_b, h_buf, 256);
        recur_kernel<<<128, 256, 0, stream>>>(h_buf, nullptr, wx_p, wh_p, b_p,
                                              hx_buf, (int*)sync_f, 0);
    }
    gemm_kernel<256, 2, 0><<<dim3(TBR / 128, 2), 256, 0, stream>>>(
        h_buf, w0, b0, z0, 256);
    gemm_kernel<256, 2, 0><<<dim3(TBR / 128, 2), 256, 0, stream>>>(
        z0, w1, b1, h_buf, 256);
    final_kernel<<<TBR / 128, 256, 0, stream>>>(h_buf, w2, b2, out);
}

// Round 3
// 4484.644 us; speedup vs baseline: 1.1142x; 1.0452x over previous
//
#include <hip/hip_runtime.h>
#include <cstdint>

#define TT 1024
#define BB 128
#define DD 512
#define HH 256
#define TBR (TT*BB)   // 131072 rows

typedef __attribute__((ext_vector_type(8))) short  s8v;     // 8 bf16 (4 VGPR)
typedef __attribute__((ext_vector_type(4))) float  f4v;     // MFMA acc
typedef __attribute__((ext_vector_type(4))) unsigned u4v;

__device__ __forceinline__ float sigf(float x) {
    return __builtin_amdgcn_rcpf(1.0f + __expf(-x));
}
__device__ __forceinline__ float tanh_fast(float x) {
    float e = __expf(fabsf(x) * 2.0f);
    float t = 1.0f - 2.0f * __builtin_amdgcn_rcpf(e + 1.0f);
    return copysignf(t, x);
}

__device__ __forceinline__ unsigned rnbf(float f) {         // fp32 -> bf16 bits (RN)
    unsigned u = __builtin_bit_cast(unsigned, f);
    return (u + 0x7FFFu + ((u >> 16) & 1u)) >> 16;
}

// ---------------------------------------------------------------------------
// Old packing (fallback path): r = gate*256 + h.
// ---------------------------------------------------------------------------
__global__ __launch_bounds__(256) void pack_kernel(
    const float* __restrict__ fw, const float* __restrict__ iw,
    const float* __restrict__ uw, const float* __restrict__ ow,
    const float* __restrict__ fb, const float* __restrict__ ib,
    const float* __restrict__ ub, const float* __restrict__ obb,
    float* __restrict__ wx_p, float* __restrict__ wh_p, float* __restrict__ b_p)
{
    const int r = blockIdx.x;
    const int gate = r >> 8, h = r & 255;
    const float* wsrc = gate == 0 ? fw : gate == 1 ? iw : gate == 2 ? uw : ow;
    const float* bsrc = gate == 0 ? fb : gate == 1 ? ib : gate == 2 ? ub : obb;
    const int k = threadIdx.x;
    wx_p[(size_t)r * 256 + k] = wsrc[(size_t)h * 512 + k];
    wh_p[(size_t)r * 256 + k] = wsrc[(size_t)h * 512 + 256 + k];
    if (k == 0) b_p[r] = bsrc[h];
}

// ---------------------------------------------------------------------------
// MFMA packing: r = hg*128 + g*32 + hrem, h = hg*32 + hrem  (hg=0..7).
// ---------------------------------------------------------------------------
__global__ __launch_bounds__(256) void pack_mfma(
    const float* __restrict__ fw, const float* __restrict__ iw,
    const float* __restrict__ uw, const float* __restrict__ ow,
    const float* __restrict__ fb, const float* __restrict__ ib,
    const float* __restrict__ ub, const float* __restrict__ obb,
    float* __restrict__ wx_p, float* __restrict__ wh_p, float* __restrict__ b_p)
{
    const int r = blockIdx.x;                 // 0..1023
    const int gate = (r >> 5) & 3;
    const int h = (r >> 7) * 32 + (r & 31);
    const float* wsrc = gate == 0 ? fw : gate == 1 ? iw : gate == 2 ? uw : ow;
    const float* bsrc = gate == 0 ? fb : gate == 1 ? ib : gate == 2 ? ub : obb;
    const int k = threadIdx.x;
    wx_p[(size_t)r * 256 + k] = wsrc[(size_t)h * 512 + k];
    wh_p[(size_t)r * 256 + k] = wsrc[(size_t)h * 512 + 256 + k];
    if (k == 0) b_p[r] = bsrc[h];
}

// ---------------------------------------------------------------------------
// fp32 GEMM: C[m][n] = act(dot(A[m][:K], W[n][:K]) + bias[n]). 128x128 tile.
// ---------------------------------------------------------------------------
template<int K, int ACT, int PERM>
__global__ __launch_bounds__(256) void gemm_kernel(
    const float* A, const float* __restrict__ W,
    const float* __restrict__ bias, float* C, int N)
{
    __shared__ __align__(16) float As[16][192];
    __shared__ __align__(16) float Wt[16][192];
    const int tid = threadIdx.x;
    const int m0 = blockIdx.x * 128, n0 = blockIdx.y * 128;
    const int tm = tid >> 4, tn = tid & 15;
    const int am = tm * 12, wn = tn * 12;
    float acc[8][8] = {};
    for (int kc = 0; kc < K; kc += 16) {
        #pragma unroll
        for (int i = 0; i < 2; ++i) {
            int f4 = tid + 256 * i;
            int r = f4 >> 2, k4 = (f4 & 3) * 4;
            float4 av = *(const float4*)&A[(size_t)(m0 + r) * K + kc + k4];
            float4 wv = *(const float4*)&W[(size_t)(n0 + r) * K + kc + k4];
            int fo = (r >> 3) * 12 + (r & 7);
            As[k4 + 0][fo] = av.x; As[k4 + 1][fo] = av.y;
            As[k4 + 2][fo] = av.z; As[k4 + 3][fo] = av.w;
            Wt[k4 + 0][fo] = wv.x; Wt[k4 + 1][fo] = wv.y;
            Wt[k4 + 2][fo] = wv.z; Wt[k4 + 3][fo] = wv.w;
        }
        __syncthreads();
        #pragma unroll
        for (int kk = 0; kk < 16; ++kk) {
            float a[8], w[8];
            *(float4*)&a[0] = *(const float4*)&As[kk][am];
            *(float4*)&a[4] = *(const float4*)&As[kk][am + 4];
            *(float4*)&w[0] = *(const float4*)&Wt[kk][wn];
            *(float4*)&w[4] = *(const float4*)&Wt[kk][wn + 4];
            #pragma unroll
            for (int i = 0; i < 8; ++i)
                #pragma unroll
                for (int j = 0; j < 8; ++j)
                    acc[i][j] = fmaf(a[i], w[j], acc[i][j]);
        }
        __syncthreads();
    }
    #pragma unroll
    for (int i = 0; i < 8; ++i) {
        int m = m0 + tm * 8 + i;
        #pragma unroll
        for (int jh = 0; jh < 2; ++jh) {
            float4 v; float* vp = (float*)&v;
            #pragma unroll
            for (int l = 0; l < 4; ++l) {
                int n = n0 + tn * 8 + jh * 4 + l;
                float t = acc[i][jh * 4 + l] + bias[n];
                if (ACT == 1) t = tanhf(t);
                if (ACT == 2) t = fmaxf(t, 0.0f);
                vp[l] = t;
            }
            int nb = n0 + tn * 8 + jh * 4;
            int nc = PERM ? (((nb & 255) >> 3) * 32 + ((nb >> 8) << 3) + (nb & 7)) : nb;
            *(float4*)&C[(size_t)m * N + nc] = v;
        }
    }
}

// ---------------------------------------------------------------------------
// Fused MFMA recurrence: Wx*h_fc AND Wh*h(t-1), sentinel-ring sync.
// 64 WGs = 8 bg(16 batches) x 8 hg(128 packed gate rows). Wh AND Wx resident
// in VGPRs as split-bf16 (hi+lo) B-fragments (~256 VGPR for weights).
//
// Per step (3 barriers):
//   a. stage h_fc(t) from regs (prefetched last step) -> ldsX split-bf16
//   b. B1
//   c. Wx MFMAs (48) -> acc  [independent of peers: rides in the shadow of
//      the peers' publish->L3 propagation]
//   d. poll sentinel ring slot (t-1)&3 -> stage hx -> ldsH/L; re-sentinel
//      slot (t-2)&3 (safe: poll success proves group consumed it)
//   e. prefetch h_fc(t+1) -> regs (consumed next step: ~1500cy of slack)
//   f. B2
//   g. Wh MFMAs (48) accumulate into acc
//   h. C-frag -> pre[] exchange
//   i. B3
//   j. combine: gates = act(pre + bias); cx update
//   k. publish 8B self-validating atom to ring + hs fp32 -> h_buf
//
// Hazard check (all verified pairwise): ldsX writes(t+1) after B3(t), readers
// (c,t) before B2(t). ldsH writes(d,t+1) after B1(t+1)>B3(t), readers (g,t)
// before B3(t). pre writes(h,t+1) after B2(t+1), readers (j,t) before B1(t+1).
// ---------------------------------------------------------------------------
__global__ __launch_bounds__(256, 1) void recur_mfma(
    float* __restrict__ h_buf,            // out: hs [T][B][256] fp32
    const float* __restrict__ hfc,        // in: tanh(fc) [T][B][256] fp32
    const float* __restrict__ wx_mf,      // [1024][256] packed
    const float* __restrict__ wh_mf,      // [1024][256] packed
    const float* __restrict__ b_mf,       // [1024] packed bias
    unsigned long long* __restrict__ ring) // [4][128][128] 8B atoms, 0xFF-filled
{
    __shared__ __align__(16) unsigned ldsH[16 * 128];
    __shared__ __align__(16) unsigned ldsL[16 * 128];
    __shared__ __align__(16) unsigned ldsXH[16 * 128];
    __shared__ __align__(16) unsigned ldsXL[16 * 128];
    __shared__ float pre[16][132];
    const int tid = threadIdx.x;
    const int lane = tid & 63;
    const int wv = tid >> 6;
    const int bg = blockIdx.x & 7, hg = blockIdx.x >> 3;
    const int b0 = bg * 16;
    const int nlo = lane & 15, quad = lane >> 4;

    // ---- one-time: Wh and Wx -> registers as split-bf16 B-fragments
    s8v bh[2][8], bl[2][8];   // Wh hi/lo
    s8v ch[2][8], cl[2][8];   // Wx hi/lo
#define PACK_FRAGS(SRCPTR, BH, BL)                                            \
    _Pragma("unroll")                                                         \
    for (int nt = 0; nt < 2; ++nt) {                                          \
        int r = hg * 128 + wv * 32 + nt * 16 + nlo;                           \
        _Pragma("unroll")                                                     \
        for (int ks = 0; ks < 8; ++ks) {                                      \
            const float* src = SRCPTR + (size_t)r * 256 + ks * 32 + quad * 8; \
            u4v uh, ul;                                                       \
            _Pragma("unroll")                                                 \
            for (int p = 0; p < 4; ++p) {                                     \
                float f0 = src[2 * p], f1 = src[2 * p + 1];                   \
                unsigned h0 = rnbf(f0), h1 = rnbf(f1);                        \
                float r0 = f0 - __builtin_bit_cast(float, h0 << 16);          \
                float r1 = f1 - __builtin_bit_cast(float, h1 << 16);          \
                uh[p] = h0 | (h1 << 16);                                      \
                ul[p] = rnbf(r0) | (rnbf(r1) << 16);                          \
            }                                                                 \
            BH[nt][ks] = __builtin_bit_cast(s8v, uh);                         \
            BL[nt][ks] = __builtin_bit_cast(s8v, ul);                         \
        }                                                                     \
    }
    PACK_FRAGS(wh_mf, bh, bl)
    PACK_FRAGS(wx_mf, ch, cl)
#undef PACK_FRAGS

    const int sm = tid >> 4;             // staging row 0..15
    const int sc0 = (tid & 15) * 2;      // first of 2 dword-quads per thread
    const int cb = tid >> 4, q = tid & 15;  // combine: batch row, h-pair
    const unsigned long long SENT = ~0ull;

    // per-thread gate biases for h-pair (hg*32+2q, +1)
    float bsf[4][2];
    #pragma unroll
    for (int g = 0; g < 4; ++g) {
        bsf[g][0] = b_mf[hg * 128 + g * 32 + 2 * q];
        bsf[g][1] = b_mf[hg * 128 + g * 32 + 2 * q + 1];
    }

    const int p0 = sm * 128 + ((sc0 ^ (sm & 7)) << 2);
    const int p1 = sm * 128 + (((sc0 + 1) ^ (sm & 7)) << 2);

    // prefetch h_fc[0]: 16 floats (row sm, cols (tid&15)*16..+15)
    float4 xf[4];
    {
        const float* xr = hfc + ((size_t)0 * BB + b0 + sm) * 256 + (tid & 15) * 16;
        xf[0] = *(const float4*)&xr[0];
        xf[1] = *(const float4*)&xr[4];
        xf[2] = *(const float4*)&xr[8];
        xf[3] = *(const float4*)&xr[12];
    }

    float cx0 = 0.0f, cx1 = 0.0f;

    for (int t = 0; t < TT; ++t) {
        // (a) stage h_fc(t): convert prefetched regs to split-bf16 planes
        {
            const float* fv = (const float*)xf;
            u4v xh0, xl0, xh1, xl1;
            #pragma unroll
            for (int p = 0; p < 4; ++p) {
                float f0 = fv[2 * p], f1 = fv[2 * p + 1];
                unsigned h0 = rnbf(f0), h1 = rnbf(f1);
                xh0[p] = h0 | (h1 << 16);
                xl0[p] = rnbf(f0 - __builtin_bit_cast(float, h0 << 16)) |
                         (rnbf(f1 - __builtin_bit_cast(float, h1 << 16)) << 16);
                float g0 = fv[8 + 2 * p], g1 = fv[8 + 2 * p + 1];
                unsigned k0 = rnbf(g0), k1 = rnbf(g1);
                xh1[p] = k0 | (k1 << 16);
                xl1[p] = rnbf(g0 - __builtin_bit_cast(float, k0 << 16)) |
                         (rnbf(g1 - __builtin_bit_cast(float, k1 << 16)) << 16);
            }
            *(u4v*)&ldsXH[p0] = xh0; *(u4v*)&ldsXH[p1] = xh1;
            *(u4v*)&ldsXL[p0] = xl0; *(u4v*)&ldsXL[p1] = xl1;
        }
        __syncthreads();   // B1

        // (c) Wx MFMAs (independent of peers — shadows publish propagation)
        f4v acc0 = {0.f, 0.f, 0.f, 0.f}, acc1 = {0.f, 0.f, 0.f, 0.f};
        #pragma unroll
        for (int ks = 0; ks < 8; ++ks) {
            int off = nlo * 128 + ((((ks * 4 + quad) ^ (nlo & 7))) << 2);
            s8v ah = __builtin_bit_cast(s8v, *(const u4v*)&ldsXH[off]);
            s8v al = __builtin_bit_cast(s8v, *(const u4v*)&ldsXL[off]);
            acc0 = __builtin_amdgcn_mfma_f32_16x16x32_bf16(ah, ch[0][ks], acc0, 0, 0, 0);
            acc1 = __builtin_amdgcn_mfma_f32_16x16x32_bf16(ah, ch[1][ks], acc1, 0, 0, 0);
            acc0 = __builtin_amdgcn_mfma_f32_16x16x32_bf16(al, ch[0][ks], acc0, 0, 0, 0);
            acc1 = __builtin_amdgcn_mfma_f32_16x16x32_bf16(al, ch[1][ks], acc1, 0, 0, 0);
            acc0 = __builtin_amdgcn_mfma_f32_16x16x32_bf16(ah, cl[0][ks], acc0, 0, 0, 0);
            acc1 = __builtin_amdgcn_mfma_f32_16x16x32_bf16(ah, cl[1][ks], acc1, 0, 0, 0);
        }

        // (d) hx stage: poll directly on the data (sentinel = ~0)
        if (t == 0) {
            u4v z = {0u, 0u, 0u, 0u};
            *(u4v*)&ldsH[p0] = z; *(u4v*)&ldsH[p1] = z;
            *(u4v*)&ldsL[p0] = z; *(u4v*)&ldsL[p1] = z;
        } else {
            unsigned long long* src =
                ring + ((size_t)((t - 1) & 3) * 128 + b0 + sm) * 128 + sc0 * 4;
            unsigned long long a[8];
            long bud = 1L << 22;
            for (;;) {
                #pragma unroll
                for (int i = 0; i < 8; ++i)
                    a[i] = __hip_atomic_load(&src[i], __ATOMIC_RELAXED,
                                             __HIP_MEMORY_SCOPE_AGENT);
                bool ok = true;
                #pragma unroll
                for (int i = 0; i < 8; ++i) ok = ok && (a[i] != SENT);
                if (__all(ok)) break;
                if (--bud < 0) break;
                __builtin_amdgcn_s_sleep(1);
            }
            u4v w0 = { (unsigned)a[0], (unsigned)a[1], (unsigned)a[2], (unsigned)a[3] };
            u4v w1 = { (unsigned)a[4], (unsigned)a[5], (unsigned)a[6], (unsigned)a[7] };
            u4v v0 = { (unsigned)(a[0] >> 32), (unsigned)(a[1] >> 32),
                       (unsigned)(a[2] >> 32), (unsigned)(a[3] >> 32) };
            u4v v1 = { (unsigned)(a[4] >> 32), (unsigned)(a[5] >> 32),
                       (unsigned)(a[6] >> 32), (unsigned)(a[7] >> 32) };
            *(u4v*)&ldsH[p0] = w0; *(u4v*)&ldsH[p1] = w1;
            *(u4v*)&ldsL[p0] = v0; *(u4v*)&ldsL[p1] = v1;
            if (t >= 2) {
                __hip_atomic_store(
                    &ring[((size_t)((t - 2) & 3) * 128 + b0 + cb) * 128 + hg * 16 + q],
                    SENT, __ATOMIC_RELAXED, __HIP_MEMORY_SCOPE_AGENT);
            }
        }

        // (e) prefetch h_fc(t+1) — consumed at (a) next step (~1500cy slack)
        {
            int tn2 = (t + 1 < TT) ? (t + 1) : (TT - 1);
            const float* xr = hfc + ((size_t)tn2 * BB + b0 + sm) * 256 + (tid & 15) * 16;
            xf[0] = *(const float4*)&xr[0];
            xf[1] = *(const float4*)&xr[4];
            xf[2] = *(const float4*)&xr[8];
            xf[3] = *(const float4*)&xr[12];
        }
        __syncthreads();   // B2

        // (g) Wh MFMAs accumulate into the same acc
        #pragma unroll
        for (int ks = 0; ks < 8; ++ks) {
            int off = nlo * 128 + ((((ks * 4 + quad) ^ (nlo & 7))) << 2);
            s8v ah = __builtin_bit_cast(s8v, *(const u4v*)&ldsH[off]);
            s8v al = __builtin_bit_cast(s8v, *(const u4v*)&ldsL[off]);
            acc0 = __builtin_amdgcn_mfma_f32_16x16x32_bf16(ah, bh[0][ks], acc0, 0, 0, 0);
            acc1 = __builtin_amdgcn_mfma_f32_16x16x32_bf16(ah, bh[1][ks], acc1, 0, 0, 0);
            acc0 = __builtin_amdgcn_mfma_f32_16x16x32_bf16(al, bh[0][ks], acc0, 0, 0, 0);
            acc1 = __builtin_amdgcn_mfma_f32_16x16x32_bf16(al, bh[1][ks], acc1, 0, 0, 0);
            acc0 = __builtin_amdgcn_mfma_f32_16x16x32_bf16(ah, bl[0][ks], acc0, 0, 0, 0);
            acc1 = __builtin_amdgcn_mfma_f32_16x16x32_bf16(ah, bl[1][ks], acc1, 0, 0, 0);
        }
        // (h) C-frags -> pre[m][n]
        {
            int n0c = wv * 32 + nlo;
            #pragma unroll
            for (int reg = 0; reg < 4; ++reg) {
                pre[quad * 4 + reg][n0c]      = acc0[reg];
                pre[quad * 4 + reg][n0c + 16] = acc1[reg];
            }
        }
        __syncthreads();   // B3

        // (j) local gate combine (bias added here now)
        float2 pf = *(const float2*)&pre[cb][0 * 32 + 2 * q];
        float2 pi = *(const float2*)&pre[cb][1 * 32 + 2 * q];
        float2 pg = *(const float2*)&pre[cb][2 * 32 + 2 * q];
        float2 po = *(const float2*)&pre[cb][3 * 32 + 2 * q];
        float f0 = sigf(pf.x + bsf[0][0]), f1 = sigf(pf.y + bsf[0][1]);
        float i0 = sigf(pi.x + bsf[1][0]), i1 = sigf(pi.y + bsf[1][1]);
        float g0 = tanh_fast(pg.x + bsf[2][0]), g1 = tanh_fast(pg.y + bsf[2][1]);
        float o0 = sigf(po.x + bsf[3][0]), o1 = sigf(po.y + bsf[3][1]);
        cx0 = f0 * cx0 + i0 * g0;
        cx1 = f1 * cx1 + i1 * g1;
        float hv0 = o0 * tanh_fast(cx0);
        float hv1 = o1 * tanh_fast(cx1);

        // (k) publish: 8B self-validating atom + hs fp32
        unsigned hb0 = rnbf(hv0), hb1 = rnbf(hv1);
        float l0 = hv0 - __builtin_bit_cast(float, hb0 << 16);
        float l1 = hv1 - __builtin_bit_cast(float, hb1 << 16);
        unsigned long long atom =
            (unsigned long long)(hb0 | (hb1 << 16)) |
            ((unsigned long long)(rnbf(l0) | (rnbf(l1) << 16)) << 32);
        __hip_atomic_store(
            &ring[((size_t)(t & 3) * 128 + b0 + cb) * 128 + hg * 16 + q],
            atom, __ATOMIC_RELAXED, __HIP_MEMORY_SCOPE_AGENT);
        *(float2*)&h_buf[((size_t)t * BB + b0 + cb) * 256 + hg * 32 + 2 * q] =
            make_float2(hv0, hv1);
    }
}

// ---------------------------------------------------------------------------
// Fallback scalar recurrence (old packing), used if ws too small.
// ---------------------------------------------------------------------------
__device__ __forceinline__ int swz(int row, int k4) {
    return row * 256 + (((k4 ^ (row & 7)) & 63) << 2);
}

__global__ __launch_bounds__(256, 1) void recur_kernel(
    float* h_buf, const float* __restrict__ xg,
    const float* __restrict__ wx_p, const float* __restrict__ wh_p,
    const float* __restrict__ b_p, float* hx_buf, int* flags, int use_xg)
{
    __shared__ __align__(16) float Ws[32 * 256];
    __shared__ __align__(16) float Ss[32 * 256];
    const int tid = threadIdx.x;
    const int lane = tid & 63;
    const int bg = blockIdx.x & 3, hg = blockIdx.x >> 2;
    const int b0 = bg * 32;
    const int b = tid >> 3, h = tid & 7;
    const int wrow = tid >> 3;
    const int wkb = (tid & 7) * 32;

    float bias0 = b_p[0 * 256 + hg * 8 + h];
    float bias1 = b_p[1 * 256 + hg * 8 + h];
    float bias2 = b_p[2 * 256 + hg * 8 + h];
    float bias3 = b_p[3 * 256 + hg * 8 + h];
    __syncthreads();

    float cx = 0.0f, pv = 0.0f;

    for (int t = 0; t < TT; ++t) {
        if (t > 0) {
            const int* fp = flags + (size_t)(t - 1) * 128 + bg * 32 + (lane & 31);
            long bud = 1L << 22;
            for (;;) {
                int v = __hip_atomic_load(fp, __ATOMIC_RELAXED, __HIP_MEMORY_SCOPE_AGENT);
                if (__all(v != 0)) break;
                if (--bud < 0) break;
                __builtin_amdgcn_s_sleep(1);
            }
        }
        float acc0, acc1, acc2, acc3;
        {
            if (t > 0)
                h_buf[((size_t)(t - 1) * BB + b0 + b) * 256 + hg * 8 + h] = pv;
            acc0 = bias0; acc1 = bias1; acc2 = bias2; acc3 = bias3;
            {
                const int R = (wrow >> 3) * 256 + hg * 8 + (wrow & 7);
                const float* src = wx_p + (size_t)R * 256 + wkb;
                #pragma unroll
                for (int j = 0; j < 8; ++j)
                    *(float4*)&Ws[swz(wrow, (wkb >> 2) + j)] = *(const float4*)&src[j * 4];
                const float* hs = h_buf + ((size_t)t * BB + b0) * HH;
                #pragma unroll
                for (int i = 0; i < 32; ++i)
                    Ss[i * 256 + ((((tid >> 2) ^ (i & 7)) & 63) << 2) + (tid & 3)] =
                        hs[i * 256 + tid];
            }
            __syncthreads();
            #pragma unroll 4
            for (int k4 = 0; k4 < 64; ++k4) {
                float4 s  = *(const float4*)&Ss[swz(b, k4)];
                float4 w0 = *(const float4*)&Ws[(0 * 8 + h) * 256 + (((k4 ^ h) & 63) << 2)];
                float4 w1 = *(const float4*)&Ws[(1 * 8 + h) * 256 + (((k4 ^ h) & 63) << 2)];
                float4 w2 = *(const float4*)&Ws[(2 * 8 + h) * 256 + (((k4 ^ h) & 63) << 2)];
                float4 w3 = *(const float4*)&Ws[(3 * 8 + h) * 256 + (((k4 ^ h) & 63) << 2)];
                acc0 += s.x*w0.x + s.y*w0.y + s.z*w0.z + s.w*w0.w;
                acc1 += s.x*w1.x + s.y*w1.y + s.z*w1.z + s.w*w1.w;
                acc2 += s.x*w2.x + s.y*w2.y + s.z*w2.z + s.w*w2.w;
                acc3 += s.x*w3.x + s.y*w3.y + s.z*w3.z + s.w*w3.w;
            }
            __syncthreads();
            {
                const int R = (wrow >> 3) * 256 + hg * 8 + (wrow & 7);
                const float* src = wh_p + (size_t)R * 256 + wkb;
                #pragma unroll
                for (int j = 0; j < 8; ++j)
                    *(float4*)&Ws[swz(wrow, (wkb >> 2) + j)] = *(const float4*)&src[j * 4];
            }
        }
        {
            const float* hxr = hx_buf + (size_t)(t & 1) * (BB * HH) + (size_t)b0 * HH;
            #pragma unroll
            for (int i = 0; i < 32; ++i) {
                float v = __hip_atomic_load(&hxr[i * 256 + tid],
                                            __ATOMIC_RELAXED, __HIP_MEMORY_SCOPE_AGENT);
                Ss[i * 256 + ((((tid >> 2) ^ (i & 7)) & 63) << 2) + (tid & 3)] = v;
            }
        }
        __syncthreads();
        #pragma unroll 4
        for (int k4 = 0; k4 < 64; ++k4) {
            float4 s  = *(const float4*)&Ss[swz(b, k4)];
            float4 w0 = *(const float4*)&Ws[(0 * 8 + h) * 256 + (((k4 ^ h) & 63) << 2)];
            float4 w1 = *(const float4*)&Ws[(1 * 8 + h) * 256 + (((k4 ^ h) & 63) << 2)];
            float4 w2 = *(const float4*)&Ws[(2 * 8 + h) * 256 + (((k4 ^ h) & 63) << 2)];
            float4 w3 = *(const float4*)&Ws[(3 * 8 + h) * 256 + (((k4 ^ h) & 63) << 2)];
            acc0 += s.x*w0.x + s.y*w0.y + s.z*w0.z + s.w*w0.w;
            acc1 += s.x*w1.x + s.y*w1.y + s.z*w1.z + s.w*w1.w;
            acc2 += s.x*w2.x + s.y*w2.y + s.z*w2.z + s.w*w2.w;
            acc3 += s.x*w3.x + s.y*w3.y + s.z*w3.z + s.w*w3.w;
        }
        __syncthreads();

        float fg = sigf(acc0), ig = sigf(acc1), gg = tanhf(acc2), og = sigf(acc3);
        cx = fg * cx + ig * gg;
        float hxv = og * tanhf(cx);
        pv = hxv;

        __hip_atomic_store(
            &hx_buf[(size_t)((t + 1) & 1) * (BB * HH) + (size_t)(b0 + b) * HH + hg * 8 + h],
            hxv, __ATOMIC_RELAXED, __HIP_MEMORY_SCOPE_AGENT);
        asm volatile("s_waitcnt vmcnt(0)" ::: "memory");
        __syncthreads();
        if (tid == 0)
            __hip_atomic_store(&flags[(size_t)t * 128 + bg * 32 + hg], 1,
                               __ATOMIC_RELAXED, __HIP_MEMORY_SCOPE_AGENT);
    }

    {
        const int* fp = flags + (size_t)1023 * 128 + bg * 32 + (lane & 31);
        long bud = 1L << 22;
        for (;;) {
            int v = __hip_atomic_load(fp, __ATOMIC_RELAXED, __HIP_MEMORY_SCOPE_AGENT);
            if (__all(v != 0)) break;
            if (--bud < 0) break;
            __builtin_amdgcn_s_sleep(1);
        }
        h_buf[((size_t)1023 * BB + b0 + b) * 256 + hg * 8 + h] = pv;
    }
}

// ---------------------------------------------------------------------------
__global__ __launch_bounds__(256) void final_kernel(
    const float* __restrict__ z, const float* __restrict__ w2,
    const float* __restrict__ b2, float* __restrict__ out)
{
    const int m = blockIdx.x * 128 + (threadIdx.x >> 1);
    const int c = threadIdx.x & 1;
    const float* zr = z + (size_t)m * 256;
    const float* wr = w2 + (size_t)c * 256;
    float s = b2[c];
    #pragma unroll 8
    for (int k = 0; k < 256; k += 4) {
        float4 zv = *(const float4*)&zr[k];
        float4 wv = *(const float4*)&wr[k];
        s += zv.x*wv.x + zv.y*wv.y + zv.z*wv.z + zv.w*wv.w;
    }
    out[(size_t)m * 2 + c] = s;
}

// ---------------------------------------------------------------------------
extern "C" void kernel_launch(void* const* d_in, const int* in_sizes, int n_in,
                              void* d_out, int out_size, void* d_ws, size_t ws_size,
                              hipStream_t stream) {
    const float* x    = (const float*)d_in[0];
    const float* fc_w = (const float*)d_in[1];
    const float* fc_b = (const float*)d_in[2];
    const float* fw   = (const float*)d_in[3];
    const float* fb   = (const float*)d_in[4];
    const float* iw   = (const float*)d_in[5];
    const float* ib   = (const float*)d_in[6];
    const float* uw   = (const float*)d_in[7];
    const float* ub   = (const float*)d_in[8];
    const float* ow   = (const float*)d_in[9];
    const float* ob   = (const float*)d_in[10];
    const float* w0   = (const float*)d_in[11];
    const float* b0   = (const float*)d_in[12];
    const float* w1   = (const float*)d_in[13];
    const float* b1   = (const float*)d_in[14];
    const float* w2   = (const float*)d_in[15];
    const float* b2   = (const float*)d_in[16];
    float* out = (float*)d_out;

    // Workspace layout byte-identical prefix to previous rounds.
    float* ws = (float*)d_ws;
    size_t off = 0;
    float* h_buf  = ws + off; off += (size_t)TBR * HH;     // 33,554,432 f
    float* wx_p   = ws + off; off += 1024 * 256;           // also wx_mf
    float* wh_p   = ws + off; off += 1024 * 256;           // also wh_mf
    float* b_p    = ws + off; off += 1024;                 // also b_mf
    float* hx_buf = ws + off; off += 2 * BB * HH;          // fallback only
    float* sync_f = ws + off; off += 131072;               // ring / flags
    const size_t base_f = off;
    float* hfc = ws + base_f;                              // tanh(fc) [TBR][256]
    const size_t need = (base_f + (size_t)TBR * 256) * sizeof(float);
    const int use_mfma = (ws_size >= need) ? 1 : 0;
    float* z0 = ws + base_f;                               // reused after recur

    if (use_mfma) {
        // sentinel-fill the depth-4 hx ring (4*128*128 atoms * 8B = 512 KB)
        hipMemsetAsync(sync_f, 0xFF, 131072 * sizeof(float), stream);
        pack_mfma<<<1024, 256, 0, stream>>>(fw, iw, uw, ow, fb, ib, ub, ob,
                                            wx_p, wh_p, b_p);
        // FC+tanh writes to hfc (NOT h_buf): recur reads hfc, writes hs->h_buf
        gemm_kernel<512, 1, 0><<<dim3(TBR / 128, 2), 256, 0, stream>>>(
            x, fc_w, fc_b, hfc, 256);
        recur_mfma<<<64, 256, 0, stream>>>(h_buf, hfc, wx_p, wh_p, b_p,
                                           (unsigned long long*)sync_f);
    } else {
        hipMemsetAsync(hx_buf, 0, (2 * BB * HH + 131072) * sizeof(float), stream);
        pack_kernel<<<1024, 256, 0, stream>>>(fw, iw, uw, ow, fb, ib, ub, ob,
                                              wx_p, wh_p, b_p);
        gemm_kernel<512, 1, 0><<<dim3(TBR / 128, 2), 256, 0, stream>>>(
            x, fc_w, fc_b, h_buf, 256);
        recur_kernel<<<128, 256, 0, stream>>>(h_buf, nullptr, wx_p, wh_p, b_p,
                                              hx_buf, (int*)sync_f, 0);
    }
    gemm_kernel<256, 2, 0><<<dim3(TBR / 128, 2), 256, 0, stream>>>(
        h_buf, w0, b0, z0, 256);
    gemm_kernel<256, 2, 0><<<dim3(TBR / 128, 2), 256, 0, stream>>>(
        z0, w1, b1, h_buf, 256);
    final_kernel<<<TBR / 128, 256, 0, stream>>>(h_buf, w2, b2, out);
}

// Round 4
// 4110.509 us; speedup vs baseline: 1.2156x; 1.0910x over previous
//
#include <hip/hip_runtime.h>
#include <cstdint>

#define TT 1024
#define BB 128
#define DD 512
#define HH 256
#define TBR (TT*BB)   // 131072 rows

typedef __attribute__((ext_vector_type(8))) short  s8v;     // 8 bf16 (4 VGPR)
typedef __attribute__((ext_vector_type(4))) float  f4v;     // MFMA acc
typedef __attribute__((ext_vector_type(4))) unsigned u4v;

__device__ __forceinline__ float sigf(float x) {
    return __builtin_amdgcn_rcpf(1.0f + __expf(-x));
}
__device__ __forceinline__ float tanh_fast(float x) {
    float e = __expf(fabsf(x) * 2.0f);
    float t = 1.0f - 2.0f * __builtin_amdgcn_rcpf(e + 1.0f);
    return copysignf(t, x);
}

__device__ __forceinline__ unsigned rnbf(float f) {         // fp32 -> bf16 bits (RN)
    unsigned u = __builtin_bit_cast(unsigned, f);
    return (u + 0x7FFFu + ((u >> 16) & 1u)) >> 16;
}

// lgkm-only barrier: LDS hazards need lgkmcnt(0); skipping the vmcnt(0) drain
// keeps ring-publish store acks and hfc prefetch loads OFF the critical path.
// Cross-step ring ordering is still guaranteed: vmcnt retires in-order, so any
// later poll's vmcnt wait forces all older stores complete first.
#define BAR_LGKM() do { \
    asm volatile("s_waitcnt lgkmcnt(0)" ::: "memory"); \
    __builtin_amdgcn_s_barrier(); \
} while (0)

// ---------------------------------------------------------------------------
// Old packing (fallback path): r = gate*256 + h.
// ---------------------------------------------------------------------------
__global__ __launch_bounds__(256) void pack_kernel(
    const float* __restrict__ fw, const float* __restrict__ iw,
    const float* __restrict__ uw, const float* __restrict__ ow,
    const float* __restrict__ fb, const float* __restrict__ ib,
    const float* __restrict__ ub, const float* __restrict__ obb,
    float* __restrict__ wx_p, float* __restrict__ wh_p, float* __restrict__ b_p)
{
    const int r = blockIdx.x;
    const int gate = r >> 8, h = r & 255;
    const float* wsrc = gate == 0 ? fw : gate == 1 ? iw : gate == 2 ? uw : ow;
    const float* bsrc = gate == 0 ? fb : gate == 1 ? ib : gate == 2 ? ub : obb;
    const int k = threadIdx.x;
    wx_p[(size_t)r * 256 + k] = wsrc[(size_t)h * 512 + k];
    wh_p[(size_t)r * 256 + k] = wsrc[(size_t)h * 512 + 256 + k];
    if (k == 0) b_p[r] = bsrc[h];
}

// ---------------------------------------------------------------------------
// MFMA packing: r = hg*128 + g*32 + hrem, h = hg*32 + hrem  (hg=0..7).
// ---------------------------------------------------------------------------
__global__ __launch_bounds__(256) void pack_mfma(
    const float* __restrict__ fw, const float* __restrict__ iw,
    const float* __restrict__ uw, const float* __restrict__ ow,
    const float* __restrict__ fb, const float* __restrict__ ib,
    const float* __restrict__ ub, const float* __restrict__ obb,
    float* __restrict__ wx_p, float* __restrict__ wh_p, float* __restrict__ b_p)
{
    const int r = blockIdx.x;                 // 0..1023
    const int gate = (r >> 5) & 3;
    const int h = (r >> 7) * 32 + (r & 31);
    const float* wsrc = gate == 0 ? fw : gate == 1 ? iw : gate == 2 ? uw : ow;
    const float* bsrc = gate == 0 ? fb : gate == 1 ? ib : gate == 2 ? ub : obb;
    const int k = threadIdx.x;
    wx_p[(size_t)r * 256 + k] = wsrc[(size_t)h * 512 + k];
    wh_p[(size_t)r * 256 + k] = wsrc[(size_t)h * 512 + 256 + k];
    if (k == 0) b_p[r] = bsrc[h];
}

// ---------------------------------------------------------------------------
// Split a fp32 [N][K] weight matrix into hi/lo bf16 planes (same layout).
// ---------------------------------------------------------------------------
__global__ __launch_bounds__(256) void pack_wsplit(
    const float* __restrict__ w, unsigned short* __restrict__ whi,
    unsigned short* __restrict__ wlo, int K)
{
    const int n = blockIdx.x;
    for (int k = threadIdx.x; k < K; k += 256) {
        float f = w[(size_t)n * K + k];
        unsigned h = rnbf(f);
        float r = f - __builtin_bit_cast(float, h << 16);
        whi[(size_t)n * K + k] = (unsigned short)h;
        wlo[(size_t)n * K + k] = (unsigned short)rnbf(r);
    }
}

// ---------------------------------------------------------------------------
// fp32 GEMM (fallback path only). 128x128 tile.
// ---------------------------------------------------------------------------
template<int K, int ACT, int PERM>
__global__ __launch_bounds__(256) void gemm_kernel(
    const float* A, const float* __restrict__ W,
    const float* __restrict__ bias, float* C, int N)
{
    __shared__ __align__(16) float As[16][192];
    __shared__ __align__(16) float Wt[16][192];
    const int tid = threadIdx.x;
    const int m0 = blockIdx.x * 128, n0 = blockIdx.y * 128;
    const int tm = tid >> 4, tn = tid & 15;
    const int am = tm * 12, wn = tn * 12;
    float acc[8][8] = {};
    for (int kc = 0; kc < K; kc += 16) {
        #pragma unroll
        for (int i = 0; i < 2; ++i) {
            int f4 = tid + 256 * i;
            int r = f4 >> 2, k4 = (f4 & 3) * 4;
            float4 av = *(const float4*)&A[(size_t)(m0 + r) * K + kc + k4];
            float4 wv = *(const float4*)&W[(size_t)(n0 + r) * K + kc + k4];
            int fo = (r >> 3) * 12 + (r & 7);
            As[k4 + 0][fo] = av.x; As[k4 + 1][fo] = av.y;
            As[k4 + 2][fo] = av.z; As[k4 + 3][fo] = av.w;
            Wt[k4 + 0][fo] = wv.x; Wt[k4 + 1][fo] = wv.y;
            Wt[k4 + 2][fo] = wv.z; Wt[k4 + 3][fo] = wv.w;
        }
        __syncthreads();
        #pragma unroll
        for (int kk = 0; kk < 16; ++kk) {
            float a[8], w[8];
            *(float4*)&a[0] = *(const float4*)&As[kk][am];
            *(float4*)&a[4] = *(const float4*)&As[kk][am + 4];
            *(float4*)&w[0] = *(const float4*)&Wt[kk][wn];
            *(float4*)&w[4] = *(const float4*)&Wt[kk][wn + 4];
            #pragma unroll
            for (int i = 0; i < 8; ++i)
                #pragma unroll
                for (int j = 0; j < 8; ++j)
                    acc[i][j] = fmaf(a[i], w[j], acc[i][j]);
        }
        __syncthreads();
    }
    #pragma unroll
    for (int i = 0; i < 8; ++i) {
        int m = m0 + tm * 8 + i;
        #pragma unroll
        for (int jh = 0; jh < 2; ++jh) {
            float4 v; float* vp = (float*)&v;
            #pragma unroll
            for (int l = 0; l < 4; ++l) {
                int n = n0 + tn * 8 + jh * 4 + l;
                float t = acc[i][jh * 4 + l] + bias[n];
                if (ACT == 1) t = tanhf(t);
                if (ACT == 2) t = fmaxf(t, 0.0f);
                vp[l] = t;
            }
            int nb = n0 + tn * 8 + jh * 4;
            int nc = PERM ? (((nb & 255) >> 3) * 32 + ((nb >> 8) << 3) + (nb & 7)) : nb;
            *(float4*)&C[(size_t)m * N + nc] = v;
        }
    }
}

// ---------------------------------------------------------------------------
// Split-bf16 3-term MFMA GEMM: C[m][n] = act(dot(A[m], W[n]) + bias[n]).
// A fp32 [M][K] (converted to split-bf16 LDS planes per 32-K chunk);
// W pre-packed hi/lo bf16 planes [N][K] (pack_wsplit). N fixed = 256.
// Block 256t = 4 waves; wave owns 32 n-cols (2 ntiles), all 128 m (8 mtiles).
// Fragment/C layouts identical to recur_mfma (harness-verified).
// ---------------------------------------------------------------------------
template<int K, int ACT>
__global__ __launch_bounds__(256) void gemm_bf16s(
    const float* __restrict__ A, const unsigned short* __restrict__ whi,
    const unsigned short* __restrict__ wlo, const float* __restrict__ bias,
    float* __restrict__ C)
{
    __shared__ __align__(16) unsigned ldsAH[128 * 16];
    __shared__ __align__(16) unsigned ldsAL[128 * 16];
    const int tid = threadIdx.x;
    const int lane = tid & 63;
    const int wv = tid >> 6;
    const int m0 = blockIdx.x * 128;
    const int n0 = blockIdx.y * 128 + wv * 32;
    const int nlo = lane & 15, quad = lane >> 4;
    const int sr = tid >> 1, sg = tid & 1;

    f4v acc[8][2];
    #pragma unroll
    for (int i = 0; i < 8; ++i) {
        acc[i][0] = f4v{0.f, 0.f, 0.f, 0.f};
        acc[i][1] = f4v{0.f, 0.f, 0.f, 0.f};
    }

    for (int kc = 0; kc < K; kc += 32) {
        // stage A chunk: fp32 -> split-bf16 planes (row sr, k-half sg)
        {
            const float* ar = A + (size_t)(m0 + sr) * K + kc + sg * 16;
            float fv[16];
            *(float4*)&fv[0]  = *(const float4*)&ar[0];
            *(float4*)&fv[4]  = *(const float4*)&ar[4];
            *(float4*)&fv[8]  = *(const float4*)&ar[8];
            *(float4*)&fv[12] = *(const float4*)&ar[12];
            u4v h0, h1, l0, l1;
            #pragma unroll
            for (int p = 0; p < 4; ++p) {
                float a0 = fv[2 * p], a1 = fv[2 * p + 1];
                unsigned x0 = rnbf(a0), x1 = rnbf(a1);
                h0[p] = x0 | (x1 << 16);
                l0[p] = rnbf(a0 - __builtin_bit_cast(float, x0 << 16)) |
                        (rnbf(a1 - __builtin_bit_cast(float, x1 << 16)) << 16);
                float c0 = fv[8 + 2 * p], c1 = fv[8 + 2 * p + 1];
                unsigned y0 = rnbf(c0), y1 = rnbf(c1);
                h1[p] = y0 | (y1 << 16);
                l1[p] = rnbf(c0 - __builtin_bit_cast(float, y0 << 16)) |
                        (rnbf(c1 - __builtin_bit_cast(float, y1 << 16)) << 16);
            }
            int base = sr * 16 + sg * 8;
            *(u4v*)&ldsAH[base]     = h0; *(u4v*)&ldsAH[base + 4] = h1;
            *(u4v*)&ldsAL[base]     = l0; *(u4v*)&ldsAL[base + 4] = l1;
        }
        __syncthreads();

        // B frags (global, L2/L3-resident small weight planes)
        s8v bhh[2], bll[2];
        #pragma unroll
        for (int nt = 0; nt < 2; ++nt) {
            size_t roff = (size_t)(n0 + nt * 16 + nlo) * K + kc + quad * 8;
            bhh[nt] = *(const s8v*)&whi[roff];
            bll[nt] = *(const s8v*)&wlo[roff];
        }
        #pragma unroll
        for (int mt = 0; mt < 8; ++mt) {
            int off = (mt * 16 + nlo) * 16 + quad * 4;
            s8v ah = __builtin_bit_cast(s8v, *(const u4v*)&ldsAH[off]);
            s8v al = __builtin_bit_cast(s8v, *(const u4v*)&ldsAL[off]);
            acc[mt][0] = __builtin_amdgcn_mfma_f32_16x16x32_bf16(ah, bhh[0], acc[mt][0], 0, 0, 0);
            acc[mt][1] = __builtin_amdgcn_mfma_f32_16x16x32_bf16(ah, bhh[1], acc[mt][1], 0, 0, 0);
            acc[mt][0] = __builtin_amdgcn_mfma_f32_16x16x32_bf16(al, bhh[0], acc[mt][0], 0, 0, 0);
            acc[mt][1] = __builtin_amdgcn_mfma_f32_16x16x32_bf16(al, bhh[1], acc[mt][1], 0, 0, 0);
            acc[mt][0] = __builtin_amdgcn_mfma_f32_16x16x32_bf16(ah, bll[0], acc[mt][0], 0, 0, 0);
            acc[mt][1] = __builtin_amdgcn_mfma_f32_16x16x32_bf16(ah, bll[1], acc[mt][1], 0, 0, 0);
        }
        __syncthreads();
    }

    float bv0 = bias[n0 + nlo];
    float bv1 = bias[n0 + 16 + nlo];
    #pragma unroll
    for (int mt = 0; mt < 8; ++mt) {
        #pragma unroll
        for (int nt = 0; nt < 2; ++nt) {
            float bv = nt ? bv1 : bv0;
            int n = n0 + nt * 16 + nlo;
            #pragma unroll
            for (int reg = 0; reg < 4; ++reg) {
                float t = acc[mt][nt][reg] + bv;
                if (ACT == 1) t = tanhf(t);
                if (ACT == 2) t = fmaxf(t, 0.0f);
                C[(size_t)(m0 + mt * 16 + quad * 4 + reg) * 256 + n] = t;
            }
        }
    }
}

// ---------------------------------------------------------------------------
// Fused MFMA recurrence. Changes this round:
//  - all barriers are lgkm-only (no vmcnt(0) drain of publish stores/prefetch)
//  - poll loads + hfc(t+1) prefetch issued right after B1, Wx MFMAs run under
//    their shadow (sched_barrier pins), check after.
// Step: (a) stage hfc(t) | B1 | issue{poll,xf'} | Wx MFMA | poll-check+stage
//       | B2 | Wh MFMA | pre | B3 | combine | publish.
// ---------------------------------------------------------------------------
__global__ __launch_bounds__(256, 1) void recur_mfma(
    float* __restrict__ h_buf,            // out: hs [T][B][256] fp32
    const float* __restrict__ hfc,        // in: tanh(fc) [T][B][256] fp32
    const float* __restrict__ wx_mf,      // [1024][256] packed
    const float* __restrict__ wh_mf,      // [1024][256] packed
    const float* __restrict__ b_mf,       // [1024] packed bias
    unsigned long long* __restrict__ ring) // [4][128][128] 8B atoms, 0xFF-filled
{
    __shared__ __align__(16) unsigned ldsH[16 * 128];
    __shared__ __align__(16) unsigned ldsL[16 * 128];
    __shared__ __align__(16) unsigned ldsXH[16 * 128];
    __shared__ __align__(16) unsigned ldsXL[16 * 128];
    __shared__ float pre[16][132];
    const int tid = threadIdx.x;
    const int lane = tid & 63;
    const int wv = tid >> 6;
    const int bg = blockIdx.x & 7, hg = blockIdx.x >> 3;
    const int b0 = bg * 16;
    const int nlo = lane & 15, quad = lane >> 4;

    // ---- one-time: Wh and Wx -> registers as split-bf16 B-fragments
    s8v bh[2][8], bl[2][8];   // Wh hi/lo
    s8v ch[2][8], cl[2][8];   // Wx hi/lo
#define PACK_FRAGS(SRCPTR, BH, BL)                                            \
    _Pragma("unroll")                                                         \
    for (int nt = 0; nt < 2; ++nt) {                                          \
        int r = hg * 128 + wv * 32 + nt * 16 + nlo;                           \
        _Pragma("unroll")                                                     \
        for (int ks = 0; ks < 8; ++ks) {                                      \
            const float* src = SRCPTR + (size_t)r * 256 + ks * 32 + quad * 8; \
            u4v uh, ul;                                                       \
            _Pragma("unroll")                                                 \
            for (int p = 0; p < 4; ++p) {                                     \
                float f0 = src[2 * p], f1 = src[2 * p + 1];                   \
                unsigned h0 = rnbf(f0), h1 = rnbf(f1);                        \
                float r0 = f0 - __builtin_bit_cast(float, h0 << 16);          \
                float r1 = f1 - __builtin_bit_cast(float, h1 << 16);          \
                uh[p] = h0 | (h1 << 16);                                      \
                ul[p] = rnbf(r0) | (rnbf(r1) << 16);                          \
            }                                                                 \
            BH[nt][ks] = __builtin_bit_cast(s8v, uh);                         \
            BL[nt][ks] = __builtin_bit_cast(s8v, ul);                         \
        }                                                                     \
    }
    PACK_FRAGS(wh_mf, bh, bl)
    PACK_FRAGS(wx_mf, ch, cl)
#undef PACK_FRAGS

    const int sm = tid >> 4;             // staging row 0..15
    const int sc0 = (tid & 15) * 2;      // first of 2 dword-quads per thread
    const int cb = tid >> 4, q = tid & 15;  // combine: batch row, h-pair
    const unsigned long long SENT = ~0ull;

    float bsf[4][2];
    #pragma unroll
    for (int g = 0; g < 4; ++g) {
        bsf[g][0] = b_mf[hg * 128 + g * 32 + 2 * q];
        bsf[g][1] = b_mf[hg * 128 + g * 32 + 2 * q + 1];
    }

    const int p0 = sm * 128 + ((sc0 ^ (sm & 7)) << 2);
    const int p1 = sm * 128 + (((sc0 + 1) ^ (sm & 7)) << 2);

    // prefetch h_fc[0]
    float4 xf[4];
    {
        const float* xr = hfc + ((size_t)0 * BB + b0 + sm) * 256 + (tid & 15) * 16;
        xf[0] = *(const float4*)&xr[0];
        xf[1] = *(const float4*)&xr[4];
        xf[2] = *(const float4*)&xr[8];
        xf[3] = *(const float4*)&xr[12];
    }

    float cx0 = 0.0f, cx1 = 0.0f;

    for (int t = 0; t < TT; ++t) {
        // (a) stage h_fc(t): convert prefetched regs to split-bf16 planes
        {
            const float* fv = (const float*)xf;
            u4v xh0, xl0, xh1, xl1;
            #pragma unroll
            for (int p = 0; p < 4; ++p) {
                float f0 = fv[2 * p], f1 = fv[2 * p + 1];
                unsigned h0 = rnbf(f0), h1 = rnbf(f1);
                xh0[p] = h0 | (h1 << 16);
                xl0[p] = rnbf(f0 - __builtin_bit_cast(float, h0 << 16)) |
                         (rnbf(f1 - __builtin_bit_cast(float, h1 << 16)) << 16);
                float g0 = fv[8 + 2 * p], g1 = fv[8 + 2 * p + 1];
                unsigned k0 = rnbf(g0), k1 = rnbf(g1);
                xh1[p] = k0 | (k1 << 16);
                xl1[p] = rnbf(g0 - __builtin_bit_cast(float, k0 << 16)) |
                         (rnbf(g1 - __builtin_bit_cast(float, k1 << 16)) << 16);
            }
            *(u4v*)&ldsXH[p0] = xh0; *(u4v*)&ldsXH[p1] = xh1;
            *(u4v*)&ldsXL[p0] = xl0; *(u4v*)&ldsXL[p1] = xl1;
        }
        BAR_LGKM();   // B1 (no vmcnt drain)

        // issue first poll round + hfc(t+1) prefetch; Wx covers their latency
        unsigned long long pa[8];
        const unsigned long long* srcp =
            ring + ((size_t)((t - 1) & 3) * 128 + b0 + sm) * 128 + sc0 * 4;
        if (t > 0) {
            #pragma unroll
            for (int i = 0; i < 8; ++i)
                pa[i] = __hip_atomic_load(&srcp[i], __ATOMIC_RELAXED,
                                          __HIP_MEMORY_SCOPE_AGENT);
        }
        {
            int tn2 = (t + 1 < TT) ? (t + 1) : (TT - 1);
            const float* xr = hfc + ((size_t)tn2 * BB + b0 + sm) * 256 + (tid & 15) * 16;
            xf[0] = *(const float4*)&xr[0];
            xf[1] = *(const float4*)&xr[4];
            xf[2] = *(const float4*)&xr[8];
            xf[3] = *(const float4*)&xr[12];
        }
        __builtin_amdgcn_sched_barrier(0);

        // (c) Wx MFMAs
        f4v acc0 = {0.f, 0.f, 0.f, 0.f}, acc1 = {0.f, 0.f, 0.f, 0.f};
        #pragma unroll
        for (int ks = 0; ks < 8; ++ks) {
            int off = nlo * 128 + ((((ks * 4 + quad) ^ (nlo & 7))) << 2);
            s8v ah = __builtin_bit_cast(s8v, *(const u4v*)&ldsXH[off]);
            s8v al = __builtin_bit_cast(s8v, *(const u4v*)&ldsXL[off]);
            acc0 = __builtin_amdgcn_mfma_f32_16x16x32_bf16(ah, ch[0][ks], acc0, 0, 0, 0);
            acc1 = __builtin_amdgcn_mfma_f32_16x16x32_bf16(ah, ch[1][ks], acc1, 0, 0, 0);
            acc0 = __builtin_amdgcn_mfma_f32_16x16x32_bf16(al, ch[0][ks], acc0, 0, 0, 0);
            acc1 = __builtin_amdgcn_mfma_f32_16x16x32_bf16(al, ch[1][ks], acc1, 0, 0, 0);
            acc0 = __builtin_amdgcn_mfma_f32_16x16x32_bf16(ah, cl[0][ks], acc0, 0, 0, 0);
            acc1 = __builtin_amdgcn_mfma_f32_16x16x32_bf16(ah, cl[1][ks], acc1, 0, 0, 0);
        }
        __builtin_amdgcn_sched_barrier(0);

        // (d) poll finish + hx stage
        if (t == 0) {
            u4v z = {0u, 0u, 0u, 0u};
            *(u4v*)&ldsH[p0] = z; *(u4v*)&ldsH[p1] = z;
            *(u4v*)&ldsL[p0] = z; *(u4v*)&ldsL[p1] = z;
        } else {
            bool ok = true;
            #pragma unroll
            for (int i = 0; i < 8; ++i) ok = ok && (pa[i] != SENT);
            if (!__all(ok)) {
                long bud = 1L << 22;
                for (;;) {
                    #pragma unroll
                    for (int i = 0; i < 8; ++i)
                        pa[i] = __hip_atomic_load(&srcp[i], __ATOMIC_RELAXED,
                                                  __HIP_MEMORY_SCOPE_AGENT);
                    ok = true;
                    #pragma unroll
                    for (int i = 0; i < 8; ++i) ok = ok && (pa[i] != SENT);
                    if (__all(ok)) break;
                    if (--bud < 0) break;
                    __builtin_amdgcn_s_sleep(1);
                }
            }
            u4v w0 = { (unsigned)pa[0], (unsigned)pa[1], (unsigned)pa[2], (unsigned)pa[3] };
            u4v w1 = { (unsigned)pa[4], (unsigned)pa[5], (unsigned)pa[6], (unsigned)pa[7] };
            u4v v0 = { (unsigned)(pa[0] >> 32), (unsigned)(pa[1] >> 32),
                       (unsigned)(pa[2] >> 32), (unsigned)(pa[3] >> 32) };
            u4v v1 = { (unsigned)(pa[4] >> 32), (unsigned)(pa[5] >> 32),
                       (unsigned)(pa[6] >> 32), (unsigned)(pa[7] >> 32) };
            *(u4v*)&ldsH[p0] = w0; *(u4v*)&ldsH[p1] = w1;
            *(u4v*)&ldsL[p0] = v0; *(u4v*)&ldsL[p1] = v1;
            if (t >= 2) {
                __hip_atomic_store(
                    &ring[((size_t)((t - 2) & 3) * 128 + b0 + cb) * 128 + hg * 16 + q],
                    SENT, __ATOMIC_RELAXED, __HIP_MEMORY_SCOPE_AGENT);
            }
        }
        BAR_LGKM();   // B2 (no vmcnt drain: xf prefetch stays in flight)

        // (g) Wh MFMAs accumulate into the same acc
        #pragma unroll
        for (int ks = 0; ks < 8; ++ks) {
            int off = nlo * 128 + ((((ks * 4 + quad) ^ (nlo & 7))) << 2);
            s8v ah = __builtin_bit_cast(s8v, *(const u4v*)&ldsH[off]);
            s8v al = __builtin_bit_cast(s8v, *(const u4v*)&ldsL[off]);
            acc0 = __builtin_amdgcn_mfma_f32_16x16x32_bf16(ah, bh[0][ks], acc0, 0, 0, 0);
            acc1 = __builtin_amdgcn_mfma_f32_16x16x32_bf16(ah, bh[1][ks], acc1, 0, 0, 0);
            acc0 = __builtin_amdgcn_mfma_f32_16x16x32_bf16(al, bh[0][ks], acc0, 0, 0, 0);
            acc1 = __builtin_amdgcn_mfma_f32_16x16x32_bf16(al, bh[1][ks], acc1, 0, 0, 0);
            acc0 = __builtin_amdgcn_mfma_f32_16x16x32_bf16(ah, bl[0][ks], acc0, 0, 0, 0);
            acc1 = __builtin_amdgcn_mfma_f32_16x16x32_bf16(ah, bl[1][ks], acc1, 0, 0, 0);
        }
        // (h) C-frags -> pre[m][n]
        {
            int n0c = wv * 32 + nlo;
            #pragma unroll
            for (int reg = 0; reg < 4; ++reg) {
                pre[quad * 4 + reg][n0c]      = acc0[reg];
                pre[quad * 4 + reg][n0c + 16] = acc1[reg];
            }
        }
        BAR_LGKM();   // B3

        // (j) local gate combine
        float2 pf = *(const float2*)&pre[cb][0 * 32 + 2 * q];
        float2 pi = *(const float2*)&pre[cb][1 * 32 + 2 * q];
        float2 pg = *(const float2*)&pre[cb][2 * 32 + 2 * q];
        float2 po = *(const float2*)&pre[cb][3 * 32 + 2 * q];
        float f0 = sigf(pf.x + bsf[0][0]), f1 = sigf(pf.y + bsf[0][1]);
        float i0 = sigf(pi.x + bsf[1][0]), i1 = sigf(pi.y + bsf[1][1]);
        float g0 = tanh_fast(pg.x + bsf[2][0]), g1 = tanh_fast(pg.y + bsf[2][1]);
        float o0 = sigf(po.x + bsf[3][0]), o1 = sigf(po.y + bsf[3][1]);
        cx0 = f0 * cx0 + i0 * g0;
        cx1 = f1 * cx1 + i1 * g1;
        float hv0 = o0 * tanh_fast(cx0);
        float hv1 = o1 * tanh_fast(cx1);

        // (k) publish: 8B self-validating atom + hs fp32 (never force-drained)
        unsigned hb0 = rnbf(hv0), hb1 = rnbf(hv1);
        float l0 = hv0 - __builtin_bit_cast(float, hb0 << 16);
        float l1 = hv1 - __builtin_bit_cast(float, hb1 << 16);
        unsigned long long atom =
            (unsigned long long)(hb0 | (hb1 << 16)) |
            ((unsigned long long)(rnbf(l0) | (rnbf(l1) << 16)) << 32);
        __hip_atomic_store(
            &ring[((size_t)(t & 3) * 128 + b0 + cb) * 128 + hg * 16 + q],
            atom, __ATOMIC_RELAXED, __HIP_MEMORY_SCOPE_AGENT);
        *(float2*)&h_buf[((size_t)t * BB + b0 + cb) * 256 + hg * 32 + 2 * q] =
            make_float2(hv0, hv1);
    }
}

// ---------------------------------------------------------------------------
// Fallback scalar recurrence (old packing), used if ws too small.
// ---------------------------------------------------------------------------
__device__ __forceinline__ int swz(int row, int k4) {
    return row * 256 + (((k4 ^ (row & 7)) & 63) << 2);
}

__global__ __launch_bounds__(256, 1) void recur_kernel(
    float* h_buf, const float* __restrict__ xg,
    const float* __restrict__ wx_p, const float* __restrict__ wh_p,
    const float* __restrict__ b_p, float* hx_buf, int* flags, int use_xg)
{
    __shared__ __align__(16) float Ws[32 * 256];
    __shared__ __align__(16) float Ss[32 * 256];
    const int tid = threadIdx.x;
    const int lane = tid & 63;
    const int bg = blockIdx.x & 3, hg = blockIdx.x >> 2;
    const int b0 = bg * 32;
    const int b = tid >> 3, h = tid & 7;
    const int wrow = tid >> 3;
    const int wkb = (tid & 7) * 32;

    float bias0 = b_p[0 * 256 + hg * 8 + h];
    float bias1 = b_p[1 * 256 + hg * 8 + h];
    float bias2 = b_p[2 * 256 + hg * 8 + h];
    float bias3 = b_p[3 * 256 + hg * 8 + h];
    __syncthreads();

    float cx = 0.0f, pv = 0.0f;

    for (int t = 0; t < TT; ++t) {
        if (t > 0) {
            const int* fp = flags + (size_t)(t - 1) * 128 + bg * 32 + (lane & 31);
            long bud = 1L << 22;
            for (;;) {
                int v = __hip_atomic_load(fp, __ATOMIC_RELAXED, __HIP_MEMORY_SCOPE_AGENT);
                if (__all(v != 0)) break;
                if (--bud < 0) break;
                __builtin_amdgcn_s_sleep(1);
            }
        }
        float acc0, acc1, acc2, acc3;
        {
            if (t > 0)
                h_buf[((size_t)(t - 1) * BB + b0 + b) * 256 + hg * 8 + h] = pv;
            acc0 = bias0; acc1 = bias1; acc2 = bias2; acc3 = bias3;
            {
                const int R = (wrow >> 3) * 256 + hg * 8 + (wrow & 7);
                const float* src = wx_p + (size_t)R * 256 + wkb;
                #pragma unroll
                for (int j = 0; j < 8; ++j)
                    *(float4*)&Ws[swz(wrow, (wkb >> 2) + j)] = *(const float4*)&src[j * 4];
                const float* hs = h_buf + ((size_t)t * BB + b0) * HH;
                #pragma unroll
                for (int i = 0; i < 32; ++i)
                    Ss[i * 256 + ((((tid >> 2) ^ (i & 7)) & 63) << 2) + (tid & 3)] =
                        hs[i * 256 + tid];
            }
            __syncthreads();
            #pragma unroll 4
            for (int k4 = 0; k4 < 64; ++k4) {
                float4 s  = *(const float4*)&Ss[swz(b, k4)];
                float4 w0 = *(const float4*)&Ws[(0 * 8 + h) * 256 + (((k4 ^ h) & 63) << 2)];
                float4 w1 = *(const float4*)&Ws[(1 * 8 + h) * 256 + (((k4 ^ h) & 63) << 2)];
                float4 w2 = *(const float4*)&Ws[(2 * 8 + h) * 256 + (((k4 ^ h) & 63) << 2)];
                float4 w3 = *(const float4*)&Ws[(3 * 8 + h) * 256 + (((k4 ^ h) & 63) << 2)];
                acc0 += s.x*w0.x + s.y*w0.y + s.z*w0.z + s.w*w0.w;
                acc1 += s.x*w1.x + s.y*w1.y + s.z*w1.z + s.w*w1.w;
                acc2 += s.x*w2.x + s.y*w2.y + s.z*w2.z + s.w*w2.w;
                acc3 += s.x*w3.x + s.y*w3.y + s.z*w3.z + s.w*w3.w;
            }
            __syncthreads();
            {
                const int R = (wrow >> 3) * 256 + hg * 8 + (wrow & 7);
                const float* src = wh_p + (size_t)R * 256 + wkb;
                #pragma unroll
                for (int j = 0; j < 8; ++j)
                    *(float4*)&Ws[swz(wrow, (wkb >> 2) + j)] = *(const float4*)&src[j * 4];
            }
        }
        {
            const float* hxr = hx_buf + (size_t)(t & 1) * (BB * HH) + (size_t)b0 * HH;
            #pragma unroll
            for (int i = 0; i < 32; ++i) {
                float v = __hip_atomic_load(&hxr[i * 256 + tid],
                                            __ATOMIC_RELAXED, __HIP_MEMORY_SCOPE_AGENT);
                Ss[i * 256 + ((((tid >> 2) ^ (i & 7)) & 63) << 2) + (tid & 3)] = v;
            }
        }
        __syncthreads();
        #pragma unroll 4
        for (int k4 = 0; k4 < 64; ++k4) {
            float4 s  = *(const float4*)&Ss[swz(b, k4)];
            float4 w0 = *(const float4*)&Ws[(0 * 8 + h) * 256 + (((k4 ^ h) & 63) << 2)];
            float4 w1 = *(const float4*)&Ws[(1 * 8 + h) * 256 + (((k4 ^ h) & 63) << 2)];
            float4 w2 = *(const float4*)&Ws[(2 * 8 + h) * 256 + (((k4 ^ h) & 63) << 2)];
            float4 w3 = *(const float4*)&Ws[(3 * 8 + h) * 256 + (((k4 ^ h) & 63) << 2)];
            acc0 += s.x*w0.x + s.y*w0.y + s.z*w0.z + s.w*w0.w;
            acc1 += s.x*w1.x + s.y*w1.y + s.z*w1.z + s.w*w1.w;
            acc2 += s.x*w2.x + s.y*w2.y + s.z*w2.z + s.w*w2.w;
            acc3 += s.x*w3.x + s.y*w3.y + s.z*w3.z + s.w*w3.w;
        }
        __syncthreads();

        float fg = sigf(acc0), ig = sigf(acc1), gg = tanhf(acc2), og = sigf(acc3);
        cx = fg * cx + ig * gg;
        float hxv = og * tanhf(cx);
        pv = hxv;

        __hip_atomic_store(
            &hx_buf[(size_t)((t + 1) & 1) * (BB * HH) + (size_t)(b0 + b) * HH + hg * 8 + h],
            hxv, __ATOMIC_RELAXED, __HIP_MEMORY_SCOPE_AGENT);
        asm volatile("s_waitcnt vmcnt(0)" ::: "memory");
        __syncthreads();
        if (tid == 0)
            __hip_atomic_store(&flags[(size_t)t * 128 + bg * 32 + hg], 1,
                               __ATOMIC_RELAXED, __HIP_MEMORY_SCOPE_AGENT);
    }

    {
        const int* fp = flags + (size_t)1023 * 128 + bg * 32 + (lane & 31);
        long bud = 1L << 22;
        for (;;) {
            int v = __hip_atomic_load(fp, __ATOMIC_RELAXED, __HIP_MEMORY_SCOPE_AGENT);
            if (__all(v != 0)) break;
            if (--bud < 0) break;
            __builtin_amdgcn_s_sleep(1);
        }
        h_buf[((size_t)1023 * BB + b0 + b) * 256 + hg * 8 + h] = pv;
    }
}

// ---------------------------------------------------------------------------
__global__ __launch_bounds__(256) void final_kernel(
    const float* __restrict__ z, const float* __restrict__ w2,
    const float* __restrict__ b2, float* __restrict__ out)
{
    const int m = blockIdx.x * 128 + (threadIdx.x >> 1);
    const int c = threadIdx.x & 1;
    const float* zr = z + (size_t)m * 256;
    const float* wr = w2 + (size_t)c * 256;
    float s = b2[c];
    #pragma unroll 8
    for (int k = 0; k < 256; k += 4) {
        float4 zv = *(const float4*)&zr[k];
        float4 wv = *(const float4*)&wr[k];
        s += zv.x*wv.x + zv.y*wv.y + zv.z*wv.z + zv.w*wv.w;
    }
    out[(size_t)m * 2 + c] = s;
}

// ---------------------------------------------------------------------------
extern "C" void kernel_launch(void* const* d_in, const int* in_sizes, int n_in,
                              void* d_out, int out_size, void* d_ws, size_t ws_size,
                              hipStream_t stream) {
    const float* x    = (const float*)d_in[0];
    const float* fc_w = (const float*)d_in[1];
    const float* fc_b = (const float*)d_in[2];
    const float* fw   = (const float*)d_in[3];
    const float* fb   = (const float*)d_in[4];
    const float* iw   = (const float*)d_in[5];
    const float* ib   = (const float*)d_in[6];
    const float* uw   = (const float*)d_in[7];
    const float* ub   = (const float*)d_in[8];
    const float* ow   = (const float*)d_in[9];
    const float* ob   = (const float*)d_in[10];
    const float* w0   = (const float*)d_in[11];
    const float* b0   = (const float*)d_in[12];
    const float* w1   = (const float*)d_in[13];
    const float* b1   = (const float*)d_in[14];
    const float* w2   = (const float*)d_in[15];
    const float* b2   = (const float*)d_in[16];
    float* out = (float*)d_out;

    // Workspace layout byte-identical prefix to previous rounds.
    float* ws = (float*)d_ws;
    size_t off = 0;
    float* h_buf  = ws + off; off += (size_t)TBR * HH;     // 33,554,432 f
    float* wx_p   = ws + off; off += 1024 * 256;           // also wx_mf
    float* wh_p   = ws + off; off += 1024 * 256;           // also wh_mf
    float* b_p    = ws + off; off += 1024;                 // also b_mf
    float* hx_buf = ws + off; off += 2 * BB * HH;          // fallback only
    float* sync_f = ws + off; off += 131072;               // ring / flags / W-frags
    const size_t base_f = off;
    float* hfc = ws + base_f;                              // tanh(fc) [TBR][256]
    const size_t need = (base_f + (size_t)TBR * 256) * sizeof(float);
    const int use_mfma = (ws_size >= need) ? 1 : 0;
    float* z0 = ws + base_f;                               // reused after recur

    if (use_mfma) {
        unsigned* syncu = (unsigned*)sync_f;
        // --- fc weight split planes live in sync_f BEFORE the ring init ---
        unsigned short* fchi = (unsigned short*)syncu;            // 256x512
        unsigned short* fclo = (unsigned short*)(syncu + 65536);
        pack_wsplit<<<256, 256, 0, stream>>>(fc_w, fchi, fclo, 512);
        pack_mfma<<<1024, 256, 0, stream>>>(fw, iw, uw, ow, fb, ib, ub, ob,
                                            wx_p, wh_p, b_p);
        gemm_bf16s<512, 1><<<dim3(TBR / 128, 2), 256, 0, stream>>>(
            x, fchi, fclo, fc_b, hfc);
        // --- ring init overwrites sync_f (stream-ordered after fc gemm) ---
        hipMemsetAsync(sync_f, 0xFF, 131072 * sizeof(float), stream);
        recur_mfma<<<64, 256, 0, stream>>>(h_buf, hfc, wx_p, wh_p, b_p,
                                           (unsigned long long*)sync_f);
        // --- cls weight planes reuse sync_f after recur ---
        unsigned short* w0hi = (unsigned short*)syncu;            // 256x256
        unsigned short* w0lo = (unsigned short*)(syncu + 32768);
        unsigned short* w1hi = (unsigned short*)(syncu + 65536);
        unsigned short* w1lo = (unsigned short*)(syncu + 98304);
        pack_wsplit<<<256, 256, 0, stream>>>(w0, w0hi, w0lo, 256);
        pack_wsplit<<<256, 256, 0, stream>>>(w1, w1hi, w1lo, 256);
        gemm_bf16s<256, 2><<<dim3(TBR / 128, 2), 256, 0, stream>>>(
            h_buf, w0hi, w0lo, b0, z0);
        gemm_bf16s<256, 2><<<dim3(TBR / 128, 2), 256, 0, stream>>>(
            z0, w1hi, w1lo, b1, h_buf);
    } else {
        hipMemsetAsync(hx_buf, 0, (2 * BB * HH + 131072) * sizeof(float), stream);
        pack_kernel<<<1024, 256, 0, stream>>>(fw, iw, uw, ow, fb, ib, ub, ob,
                                              wx_p, wh_p, b_p);
        gemm_kernel<512, 1, 0><<<dim3(TBR / 128, 2), 256, 0, stream>>>(
            x, fc_w, fc_b, h_buf, 256);
        recur_kernel<<<128, 256, 0, stream>>>(h_buf, nullptr, wx_p, wh_p, b_p,
                                              hx_buf, (int*)sync_f, 0);
        gemm_kernel<256, 2, 0><<<dim3(TBR / 128, 2), 256, 0, stream>>>(
            h_buf, w0, b0, z0, 256);
        gemm_kernel<256, 2, 0><<<dim3(TBR / 128, 2), 256, 0, stream>>>(
            z0, w1, b1, h_buf, 256);
    }
    final_kernel<<<TBR / 128, 256, 0, stream>>>(h_buf, w2, b2, out);
}